// Round 3
// baseline (496.770 us; speedup 1.0000x reference)
//
#include <hip/hip_runtime.h>
#include <math.h>

#define SQRTC  0.94868329805051381f       // sqrt(0.9)
#define MAXN   (0.996f/SQRTC)             // (1-PROJ_EPS)/sqrt(c)
#define OME_CLIP (1.0f - 0.996f*0.996f)   // 1 - c*maxnorm^2
#define TWO_OVER_SQRTC 2.1081851067789197f

// stable pdist from ome_x = 1-c*||x||^2, ome_y = 1-c*||y||^2, t = dot(x,y)
// identity: 1 - c*||(-x) (+) y||^2 = ome_x*ome_y / (1 - 2c t + (c x2)(c y2))
__device__ __forceinline__ float pdist_stable(float ome_x, float ome_y, float t){
    float u = 1.0f - ome_x, v = 1.0f - ome_y;   // c*x2, c*y2
    float den = fmaxf(1.0f - 1.8f*t + u*v, 1e-15f);
    float q = ome_x*ome_y/den;                   // = 1 - z^2
    q = fminf(fmaxf(q, 2.0e-7f), 1.0f);          // z-clip at 1-1e-7
    float z = sqrtf(fmaxf(1.0f - q, 0.0f));
    float at = 0.5f * logf((1.0f+z)*(1.0f+z)/q); // atanh(z)
    return TWO_OVER_SQRTC * at;
}

// expmap0 scalar part: sum=||u||^2 -> scale f (emb=u*f) and ome = 1-c*||emb||^2
__device__ __forceinline__ void expmap_scale_ome(float sum, float* fout, float* omeout){
    float nraw = sqrtf(fmaxf(sum, 1e-30f));
    float n = fmaxf(nraw, 1e-15f);
    float sn = SQRTC*n;
    float th = tanhf(sn);
    float factor = th/sn;
    float gn = factor*nraw;                      // gamma norm
    if (gn > MAXN){ *fout = factor*(MAXN/gn); *omeout = OME_CLIP; }
    else { *fout = factor; *omeout = fmaxf((1.0f-th)*(1.0f+th), 1e-12f); }
}

// max over middle axis: in (rows, red, H) -> out (rows, H), fp32
__global__ void k_rowmax(const float* __restrict__ in,
                         float* __restrict__ outp,
                         int rows, int red, int H)
{
    int idx = blockIdx.x*256 + threadIdx.x;
    if (idx >= rows*H) return;
    int row = idx / H, h = idx - row*H;
    const float* p = in + (long long)row*red*H + h;
    float m = -INFINITY;
    for (int l = 0; l < red; l++) m = fmaxf(m, p[l*H]);
    outp[idx] = m;
}

// one block per row: emb = expmap0(A_row(768) @ W(768x512)); fp32 emb + ome
__global__ __launch_bounds__(256)
void k_emb(const float* __restrict__ A, long long strideA,
           const float* __restrict__ W,
           float* __restrict__ emb, float* __restrict__ omeout)
{
    __shared__ float a[768];
    __shared__ float red[256];
    int row = blockIdx.x, t = threadIdx.x;
    for (int k = t; k < 768; k += 256) a[k] = A[(long long)row*strideA + k];
    __syncthreads();
    float acc0 = 0.f, acc1 = 0.f;
    for (int k = 0; k < 768; k++){
        float av = a[k];
        acc0 += av * W[k*512 + t];
        acc1 += av * W[k*512 + t + 256];
    }
    red[t] = acc0*acc0 + acc1*acc1; __syncthreads();
    for (int s = 128; s > 0; s >>= 1){ if (t < s) red[t] += red[t+s]; __syncthreads(); }
    float f, ome;
    expmap_scale_ome(red[0], &f, &ome);
    emb[row*512 + t]       = acc0*f;
    emb[row*512 + t + 256] = acc1*f;
    if (t == 0) omeout[row] = ome;
}

// 64x64-tile fp32-accum GEMM, fp32 in/out, fused bias+relu epilogue.
// mode 0: A row gm = A + gm*K (plain), out row = gm
// mode 1: (y1) b=gm/510, l=gm%510; A row = text + b*strideAb + (l+1)*768, K=768;  out row = b*1019+l
// mode 2: (y2) b=gm/509, l=gm%509; A row = text + b*strideAb + (l+1)*768, K=1536; out row = b*1019+510+l
__global__ __launch_bounds__(256)
void k_gemm_ep(const float* __restrict__ A,
               const float* __restrict__ Bm,
               const float* __restrict__ bias,  // null -> no bias/relu
               float* __restrict__ Out,
               int M, int K, int mode, long long strideAb)
{
    __shared__ float As[16][68];
    __shared__ float Bs[16][64];
    int t = threadIdx.x;
    int m0 = blockIdx.x*64, n0 = blockIdx.y*64;
    int ar = t >> 2, ak = (t & 3) << 2;
    int gm = m0 + ar;
    const float* Arow = nullptr;
    if (gm < M){
        if (mode == 1){ int b = gm/510, l = gm - b*510; Arow = A + (long long)b*strideAb + (long long)(l+1)*768; }
        else if (mode == 2){ int b = gm/509, l = gm - b*509; Arow = A + (long long)b*strideAb + (long long)(l+1)*768; }
        else Arow = A + (long long)gm*K;
    }
    int br = t >> 4, bc = (t & 15) << 2;
    int tx = t & 15, ty = t >> 4;
    float acc[4][4] = {};
    for (int k0 = 0; k0 < K; k0 += 16){
        float4 av = make_float4(0.f,0.f,0.f,0.f);
        if (Arow) av = *(const float4*)(Arow + k0 + ak);
        float4 bv = *(const float4*)(Bm + (long long)(k0+br)*512 + n0 + bc);
        As[ak+0][ar] = av.x; As[ak+1][ar] = av.y; As[ak+2][ar] = av.z; As[ak+3][ar] = av.w;
        *(float4*)&Bs[br][bc] = bv;
        __syncthreads();
        #pragma unroll
        for (int k = 0; k < 16; k++){
            float4 a4 = *(const float4*)&As[k][ty<<2];
            float4 b4 = *(const float4*)&Bs[k][tx<<2];
            acc[0][0] += a4.x*b4.x; acc[0][1] += a4.x*b4.y; acc[0][2] += a4.x*b4.z; acc[0][3] += a4.x*b4.w;
            acc[1][0] += a4.y*b4.x; acc[1][1] += a4.y*b4.y; acc[1][2] += a4.y*b4.z; acc[1][3] += a4.y*b4.w;
            acc[2][0] += a4.z*b4.x; acc[2][1] += a4.z*b4.y; acc[2][2] += a4.z*b4.z; acc[2][3] += a4.z*b4.w;
            acc[3][0] += a4.w*b4.x; acc[3][1] += a4.w*b4.y; acc[3][2] += a4.w*b4.z; acc[3][3] += a4.w*b4.w;
        }
        __syncthreads();
    }
    int col = n0 + (tx<<2);
    float4 bv = make_float4(0.f,0.f,0.f,0.f);
    if (bias) bv = *(const float4*)(bias + col);
    #pragma unroll
    for (int i = 0; i < 4; i++){
        int row = m0 + (ty<<2) + i;
        if (row >= M) continue;
        long long orow;
        if (mode == 1){ int b = row/510, l = row - b*510; orow = (long long)b*1019 + l; }
        else if (mode == 2){ int b = row/509, l = row - b*509; orow = (long long)b*1019 + 510 + l; }
        else orow = row;
        float v0 = acc[i][0], v1 = acc[i][1], v2 = acc[i][2], v3 = acc[i][3];
        if (bias){
            v0 = fmaxf(v0 + bv.x, 0.f); v1 = fmaxf(v1 + bv.y, 0.f);
            v2 = fmaxf(v2 + bv.z, 0.f); v3 = fmaxf(v3 + bv.w, 0.f);
        }
        float4 st = make_float4(v0, v1, v2, v3);
        *(float4*)(Out + orow*512 + col) = st;
    }
}

// in-place expmap0 over fp32 rows (rows x 512), store ome
__global__ __launch_bounds__(128)
void k_expmap(float* __restrict__ X, float* __restrict__ omeout)
{
    __shared__ float red[128];
    int row = blockIdx.x, t = threadIdx.x;
    float4 u = *(float4*)(X + (long long)row*512 + t*4);
    red[t] = u.x*u.x + u.y*u.y + u.z*u.z + u.w*u.w; __syncthreads();
    for (int s = 64; s > 0; s >>= 1){ if (t < s) red[t] += red[t+s]; __syncthreads(); }
    float f, ome;
    expmap_scale_ome(red[0], &f, &ome);
    float4 st = make_float4(u.x*f, u.y*f, u.z*f, u.w*f);
    *(float4*)(X + (long long)row*512 + t*4) = st;
    if (t == 0) omeout[row] = ome;
}

// per doc-word row: 22 dots vs doc/sum/cand embeddings -> 1/pdist
__global__ __launch_bounds__(64)
void k_dots(const float* __restrict__ dwe, const float* __restrict__ dwe_ome,
            const float* __restrict__ doc_emb, const float* __restrict__ doc_ome,
            const float* __restrict__ sum_emb, const float* __restrict__ sum_ome,
            const float* __restrict__ cand_emb, const float* __restrict__ cand_ome,
            float* __restrict__ doc_inter, float* __restrict__ sum_inter,
            float* __restrict__ cand_inter)
{
    int row = blockIdx.x;            // b*1019 + l
    int b = row / 1019;
    int l = row - b*1019;
    int lane = threadIdx.x;
    const float* xr = dwe + (long long)row*512;
    float4 x0 = *(const float4*)(xr + lane*4);
    float4 x1 = *(const float4*)(xr + 256 + lane*4);
    float ox = dwe_ome[row];
    for (int c = 0; c < 22; c++){
        const float* y; float oy;
        if (c == 0){ y = doc_emb + b*512; oy = doc_ome[b]; }
        else if (c == 1){ y = sum_emb + b*512; oy = sum_ome[b]; }
        else { int cc = c - 2; y = cand_emb + (b*20 + cc)*512; oy = cand_ome[b*20 + cc]; }
        float4 y0 = *(const float4*)(y + lane*4);
        float4 y1v = *(const float4*)(y + 256 + lane*4);
        float s = x0.x*y0.x + x0.y*y0.y + x0.z*y0.z + x0.w*y0.w
                + x1.x*y1v.x + x1.y*y1v.y + x1.z*y1v.z + x1.w*y1v.w;
        for (int off = 32; off > 0; off >>= 1) s += __shfl_xor(s, off, 64);
        float dist = pdist_stable(ox, oy, s);
        if (lane == 0){
            float inv = 1.0f/fmaxf(dist, 1e-12f);
            if (c == 0) doc_inter[row] = inv;
            else if (c == 1) sum_inter[row] = inv;
            else cand_inter[((long long)(b*20 + (c-2)))*1019 + l] = inv;
        }
    }
}

// final: blocks 0..79 -> score[b,c]; 80..83 -> summary_score[b]; fp32 out
__global__ __launch_bounds__(256)
void k_final(const float* __restrict__ doc_inter, const float* __restrict__ sum_inter,
             const float* __restrict__ cand_inter,
             const float* __restrict__ doc_emb, const float* __restrict__ doc_ome,
             const float* __restrict__ sum_emb, const float* __restrict__ sum_ome,
             const float* __restrict__ cand_emb, const float* __restrict__ cand_ome,
             float* __restrict__ out)
{
    __shared__ float r0[256], r1[256], r2[256], r3[256];
    int j = blockIdx.x, t = threadIdx.x;
    int b; const float *a, *bb, *xe, *ye;
    float ox, oy; int outIdx;
    if (j < 80){
        b = j/20;
        a  = doc_inter + b*1019;
        bb = cand_inter + (long long)j*1019;
        xe = cand_emb + j*512; ox = cand_ome[j];
        ye = doc_emb + b*512;  oy = doc_ome[b];
        outIdx = j;
    } else {
        b = j - 80;
        a  = doc_inter + b*1019;
        bb = sum_inter + b*1019;
        xe = sum_emb + b*512;  ox = sum_ome[b];
        ye = doc_emb + b*512;  oy = doc_ome[b];
        outIdx = 80 + b;
    }
    float saa = 0.f, sbb = 0.f, sab = 0.f, st = 0.f;
    for (int l = t; l < 1019; l += 256){ float av = a[l], bv = bb[l]; saa += av*av; sbb += bv*bv; sab += av*bv; }
    for (int k = t; k < 512; k += 256) st += xe[k]*ye[k];
    r0[t] = saa; r1[t] = sbb; r2[t] = sab; r3[t] = st; __syncthreads();
    for (int s = 128; s > 0; s >>= 1){
        if (t < s){ r0[t] += r0[t+s]; r1[t] += r1[t+s]; r2[t] += r2[t+s]; r3[t] += r3[t+s]; }
        __syncthreads();
    }
    if (t == 0){
        float na = fmaxf(sqrtf(r0[0]), 1e-8f);
        float nb = fmaxf(sqrtf(r1[0]), 1e-8f);
        float cosv = r2[0] / (na*nb);
        float pd = pdist_stable(ox, oy, r3[0]);
        out[outIdx] = -pd*pd + cosv;
    }
}

extern "C" void kernel_launch(void* const* d_in, const int* in_sizes, int n_in,
                              void* d_out, int out_size, void* d_ws, size_t ws_size,
                              hipStream_t stream) {
    const float* text = (const float*)d_in[0];   // (4,512,768) fp32
    const float* summ = (const float*)d_in[1];   // (4,128,768)
    const float* cand = (const float*)d_in[2];   // (4,20,128,768)
    const float* W_d  = (const float*)d_in[3];   // (768,512)
    const float* W_s  = (const float*)d_in[4];
    const float* W_c  = (const float*)d_in[5];
    const float* W_p  = (const float*)d_in[6];   // (512,512)
    const float* cw1  = (const float*)d_in[7];   // (1,768,512)
    const float* cb1  = (const float*)d_in[8];   // (512,)
    const float* cw2  = (const float*)d_in[9];   // (2,768,512) = (1536,512)
    const float* cb2  = (const float*)d_in[10];  // (512,)
    float* out = (float*)d_out;                  // 84 fp32 (score 80, summary 4)

    const int B = 4, L = 512, C = 20, H = 768;
    const long long textBatchStride = (long long)L*H;   // 393216

    char* base = (char*)d_ws;
    size_t off = 0;
    auto allocF = [&](size_t n)->float*{ float* p = (float*)(base + off); off += ((n*4) + 255) & ~(size_t)255; return p; };

    float* smax = allocF(B*H);
    float* cmax = allocF(B*C*H);
    float* doc_emb  = allocF(B*512);   float* doc_ome  = allocF(B);
    float* sum_emb  = allocF(B*512);   float* sum_ome  = allocF(B);
    float* cand_emb = allocF(B*C*512); float* cand_ome = allocF(B*C);
    float* gram = allocF(4076*512);    // (B,1019,512)
    float* dwe  = allocF(4076*512);    // doc_word pre-emb -> emb
    float* dwe_ome   = allocF(4076);
    float* doc_inter = allocF(4076);
    float* sum_inter = allocF(4076);
    float* cand_inter= allocF(B*C*1019);
    // total ~17.5 MB

    // 1. max-reductions
    k_rowmax<<<(B*H + 255)/256, 256, 0, stream>>>(summ, smax, B, 128, H);
    k_rowmax<<<(B*C*H + 255)/256, 256, 0, stream>>>(cand, cmax, B*C, 128, H);

    // 2. embedding rows (fused GEMV + expmap0)
    k_emb<<<B,   256, 0, stream>>>(text, textBatchStride, W_d, doc_emb, doc_ome);
    k_emb<<<B,   256, 0, stream>>>(smax, 768,             W_s, sum_emb, sum_ome);
    k_emb<<<B*C, 256, 0, stream>>>(cmax, 768,             W_c, cand_emb, cand_ome);

    // 3. conv GEMMs with fused bias+relu -> gram
    dim3 g1(32, 8), g2(32, 8);
    k_gemm_ep<<<g1, 256, 0, stream>>>(text, cw1, cb1, gram, 2040,  768, 1, textBatchStride);
    k_gemm_ep<<<g2, 256, 0, stream>>>(text, cw2, cb2, gram, 2036, 1536, 2, textBatchStride);

    // 4. doc_word pre-emb = gram @ W_p, then expmap0 rows
    dim3 gwp(64, 8);
    k_gemm_ep<<<gwp, 256, 0, stream>>>(gram, W_p, nullptr, dwe, 4076, 512, 0, 512);
    k_expmap<<<4076, 128, 0, stream>>>(dwe, dwe_ome);

    // 5. all pairwise dots -> 1/pdist
    k_dots<<<4076, 64, 0, stream>>>(dwe, dwe_ome, doc_emb, doc_ome, sum_emb, sum_ome,
                                    cand_emb, cand_ome, doc_inter, sum_inter, cand_inter);

    // 6. cos_sim reductions + pair pdist -> fp32 outputs
    k_final<<<84, 256, 0, stream>>>(doc_inter, sum_inter, cand_inter,
                                    doc_emb, doc_ome, sum_emb, sum_ome,
                                    cand_emb, cand_ome, out);
}

// Round 4
// 341.736 us; speedup vs baseline: 1.4537x; 1.4537x over previous
//
#include <hip/hip_runtime.h>
#include <math.h>

#define SQRTC  0.94868329805051381f       // sqrt(0.9)
#define MAXN   (0.996f/SQRTC)             // (1-PROJ_EPS)/sqrt(c)
#define OME_CLIP (1.0f - 0.996f*0.996f)   // 1 - c*maxnorm^2
#define TWO_OVER_SQRTC 2.1081851067789197f

// stable pdist from ome_x = 1-c*||x||^2, ome_y = 1-c*||y||^2, t = dot(x,y)
__device__ __forceinline__ float pdist_stable(float ome_x, float ome_y, float t){
    float u = 1.0f - ome_x, v = 1.0f - ome_y;   // c*x2, c*y2
    float den = fmaxf(1.0f - 1.8f*t + u*v, 1e-15f);
    float q = ome_x*ome_y/den;                   // = 1 - z^2
    q = fminf(fmaxf(q, 2.0e-7f), 1.0f);          // z-clip at 1-1e-7
    float z = sqrtf(fmaxf(1.0f - q, 0.0f));
    float at = 0.5f * logf((1.0f+z)*(1.0f+z)/q); // atanh(z)
    return TWO_OVER_SQRTC * at;
}

__device__ __forceinline__ void expmap_scale_ome(float sum, float* fout, float* omeout){
    float nraw = sqrtf(fmaxf(sum, 1e-30f));
    float n = fmaxf(nraw, 1e-15f);
    float sn = SQRTC*n;
    float th = tanhf(sn);
    float factor = th/sn;
    float gn = factor*nraw;
    if (gn > MAXN){ *fout = factor*(MAXN/gn); *omeout = OME_CLIP; }
    else { *fout = factor; *omeout = fmaxf((1.0f-th)*(1.0f+th), 1e-12f); }
}

// merged max-reductions: summary (4 rows, red 128) then cand (80 rows, red 128)
__global__ void k_rowmax_all(const float* __restrict__ summ, const float* __restrict__ cand,
                             float* __restrict__ smax, float* __restrict__ cmax)
{
    int idx = blockIdx.x*256 + threadIdx.x;
    const int H = 768;
    if (idx < 4*H){
        int row = idx / H, h = idx - row*H;
        const float* p = summ + (long long)row*128*H + h;
        float m = -INFINITY;
        for (int l = 0; l < 128; l++) m = fmaxf(m, p[l*H]);
        smax[idx] = m;
    } else {
        int i2 = idx - 4*H;
        if (i2 >= 80*H) return;
        int row = i2 / H, h = i2 - row*H;
        const float* p = cand + (long long)row*128*H + h;
        float m = -INFINITY;
        for (int l = 0; l < 128; l++) m = fmaxf(m, p[l*H]);
        cmax[i2] = m;
    }
}

// merged embedding rows: grid 88. 0..3 doc, 4..7 sum, 8..87 cand
__global__ __launch_bounds__(256)
void k_emb_all(const float* __restrict__ text,
               const float* __restrict__ smaxv, const float* __restrict__ cmaxv,
               const float* __restrict__ W_d, const float* __restrict__ W_s, const float* __restrict__ W_c,
               float* __restrict__ doc_emb, float* __restrict__ doc_ome,
               float* __restrict__ sum_emb, float* __restrict__ sum_ome,
               float* __restrict__ cand_emb, float* __restrict__ cand_ome)
{
    __shared__ float a[768];
    __shared__ float red[256];
    int row = blockIdx.x, t = threadIdx.x;
    const float* A; const float* W; float* emb; float* ome;
    if (row < 4){ A = text + (long long)row*512*768; W = W_d; emb = doc_emb + row*512; ome = doc_ome + row; }
    else if (row < 8){ int r = row-4; A = smaxv + r*768; W = W_s; emb = sum_emb + r*512; ome = sum_ome + r; }
    else { int r = row-8; A = cmaxv + r*768; W = W_c; emb = cand_emb + r*512; ome = cand_ome + r; }
    for (int k = t; k < 768; k += 256) a[k] = A[k];
    __syncthreads();
    float acc0 = 0.f, acc1 = 0.f;
    #pragma unroll 4
    for (int k = 0; k < 768; k++){
        float av = a[k];
        acc0 += av * W[k*512 + t];
        acc1 += av * W[k*512 + t + 256];
    }
    red[t] = acc0*acc0 + acc1*acc1; __syncthreads();
    for (int s = 128; s > 0; s >>= 1){ if (t < s) red[t] += red[t+s]; __syncthreads(); }
    float f, omev;
    expmap_scale_ome(red[0], &f, &omev);
    emb[t]       = acc0*f;
    emb[t + 256] = acc1*f;
    if (t == 0) *ome = omev;
}

// ---- shared GEMM tile body: BM=64 BN=64 BK=32, 256 threads, acc 4x4, register prefetch ----
// merged conv kernel: blockIdx.x even -> conv1 (K=768), odd -> conv2 (K=1536); mtile = x>>1 (32 each)
__global__ __launch_bounds__(256)
void k_conv(const float* __restrict__ text,
            const float* __restrict__ cw1, const float* __restrict__ cb1,
            const float* __restrict__ cw2, const float* __restrict__ cb2,
            float* __restrict__ gram)
{
    __shared__ float As[32][68];
    __shared__ float Bs[32][64];
    int job = blockIdx.x & 1;
    int m0 = (blockIdx.x >> 1) * 64;
    int n0 = blockIdx.y * 64;
    int K       = job ? 1536 : 768;
    int M       = job ? 2036 : 2040;
    int rowsPerB= job ? 509  : 510;
    int outBase = job ? 510  : 0;
    const float* Bm   = job ? cw2 : cw1;
    const float* bias = job ? cb2 : cb1;

    int t = threadIdx.x;
    int ar = t >> 2, ak = (t & 3) << 3;   // A stage: row ar(0..63), ks ak..ak+7
    int br = t >> 3, bc = (t & 7) << 3;   // B stage: row br(0..31), cols bc..bc+7
    int tx = t & 15, ty = t >> 4;

    int gm = m0 + ar;
    const float* Arow = nullptr;
    if (gm < M){
        int b = gm / rowsPerB, l = gm - b*rowsPerB;
        Arow = text + (long long)b*393216 + (long long)(l+1)*768;
    }
    float4 pa0 = make_float4(0,0,0,0), pa1 = pa0, pb0, pb1;
    if (Arow){ pa0 = *(const float4*)(Arow + ak); pa1 = *(const float4*)(Arow + ak + 4); }
    pb0 = *(const float4*)(Bm + (long long)br*512 + n0 + bc);
    pb1 = *(const float4*)(Bm + (long long)br*512 + n0 + bc + 4);

    float acc[4][4] = {};
    for (int k0 = 0; k0 < K; k0 += 32){
        As[ak+0][ar]=pa0.x; As[ak+1][ar]=pa0.y; As[ak+2][ar]=pa0.z; As[ak+3][ar]=pa0.w;
        As[ak+4][ar]=pa1.x; As[ak+5][ar]=pa1.y; As[ak+6][ar]=pa1.z; As[ak+7][ar]=pa1.w;
        *(float4*)&Bs[br][bc]   = pb0;
        *(float4*)&Bs[br][bc+4] = pb1;
        __syncthreads();
        int kn = k0 + 32;
        if (kn < K){
            if (Arow){ pa0 = *(const float4*)(Arow + kn + ak); pa1 = *(const float4*)(Arow + kn + ak + 4); }
            pb0 = *(const float4*)(Bm + (long long)(kn+br)*512 + n0 + bc);
            pb1 = *(const float4*)(Bm + (long long)(kn+br)*512 + n0 + bc + 4);
        }
        #pragma unroll
        for (int k = 0; k < 32; k++){
            float4 a4 = *(const float4*)&As[k][ty<<2];
            float4 b4 = *(const float4*)&Bs[k][tx<<2];
            acc[0][0] += a4.x*b4.x; acc[0][1] += a4.x*b4.y; acc[0][2] += a4.x*b4.z; acc[0][3] += a4.x*b4.w;
            acc[1][0] += a4.y*b4.x; acc[1][1] += a4.y*b4.y; acc[1][2] += a4.y*b4.z; acc[1][3] += a4.y*b4.w;
            acc[2][0] += a4.z*b4.x; acc[2][1] += a4.z*b4.y; acc[2][2] += a4.z*b4.z; acc[2][3] += a4.z*b4.w;
            acc[3][0] += a4.w*b4.x; acc[3][1] += a4.w*b4.y; acc[3][2] += a4.w*b4.z; acc[3][3] += a4.w*b4.w;
        }
        __syncthreads();
    }
    int col = n0 + (tx<<2);
    float4 bv = *(const float4*)(bias + col);
    #pragma unroll
    for (int i = 0; i < 4; i++){
        int row = m0 + (ty<<2) + i;
        if (row >= M) continue;
        int b = row / rowsPerB, l = row - b*rowsPerB;
        long long orow = (long long)b*1019 + outBase + l;
        float4 st = make_float4(fmaxf(acc[i][0]+bv.x, 0.f), fmaxf(acc[i][1]+bv.y, 0.f),
                                fmaxf(acc[i][2]+bv.z, 0.f), fmaxf(acc[i][3]+bv.w, 0.f));
        *(float4*)(gram + orow*512 + col) = st;
    }
}

// W_p GEMM: dwe_pre = gram(4076x512) @ W_p(512x512), no epilogue
__global__ __launch_bounds__(256)
void k_wp(const float* __restrict__ A, const float* __restrict__ Bm, float* __restrict__ Out)
{
    __shared__ float As[32][68];
    __shared__ float Bs[32][64];
    const int K = 512, M = 4076;
    int m0 = blockIdx.x * 64;
    int n0 = blockIdx.y * 64;
    int t = threadIdx.x;
    int ar = t >> 2, ak = (t & 3) << 3;
    int br = t >> 3, bc = (t & 7) << 3;
    int tx = t & 15, ty = t >> 4;

    int gm = m0 + ar;
    const float* Arow = (gm < M) ? (A + (long long)gm*512) : nullptr;
    float4 pa0 = make_float4(0,0,0,0), pa1 = pa0, pb0, pb1;
    if (Arow){ pa0 = *(const float4*)(Arow + ak); pa1 = *(const float4*)(Arow + ak + 4); }
    pb0 = *(const float4*)(Bm + (long long)br*512 + n0 + bc);
    pb1 = *(const float4*)(Bm + (long long)br*512 + n0 + bc + 4);

    float acc[4][4] = {};
    for (int k0 = 0; k0 < K; k0 += 32){
        As[ak+0][ar]=pa0.x; As[ak+1][ar]=pa0.y; As[ak+2][ar]=pa0.z; As[ak+3][ar]=pa0.w;
        As[ak+4][ar]=pa1.x; As[ak+5][ar]=pa1.y; As[ak+6][ar]=pa1.z; As[ak+7][ar]=pa1.w;
        *(float4*)&Bs[br][bc]   = pb0;
        *(float4*)&Bs[br][bc+4] = pb1;
        __syncthreads();
        int kn = k0 + 32;
        if (kn < K){
            if (Arow){ pa0 = *(const float4*)(Arow + kn + ak); pa1 = *(const float4*)(Arow + kn + ak + 4); }
            pb0 = *(const float4*)(Bm + (long long)(kn+br)*512 + n0 + bc);
            pb1 = *(const float4*)(Bm + (long long)(kn+br)*512 + n0 + bc + 4);
        }
        #pragma unroll
        for (int k = 0; k < 32; k++){
            float4 a4 = *(const float4*)&As[k][ty<<2];
            float4 b4 = *(const float4*)&Bs[k][tx<<2];
            acc[0][0] += a4.x*b4.x; acc[0][1] += a4.x*b4.y; acc[0][2] += a4.x*b4.z; acc[0][3] += a4.x*b4.w;
            acc[1][0] += a4.y*b4.x; acc[1][1] += a4.y*b4.y; acc[1][2] += a4.y*b4.z; acc[1][3] += a4.y*b4.w;
            acc[2][0] += a4.z*b4.x; acc[2][1] += a4.z*b4.y; acc[2][2] += a4.z*b4.z; acc[2][3] += a4.z*b4.w;
            acc[3][0] += a4.w*b4.x; acc[3][1] += a4.w*b4.y; acc[3][2] += a4.w*b4.z; acc[3][3] += a4.w*b4.w;
        }
        __syncthreads();
    }
    int col = n0 + (tx<<2);
    #pragma unroll
    for (int i = 0; i < 4; i++){
        int row = m0 + (ty<<2) + i;
        if (row >= M) continue;
        *(float4*)(Out + (long long)row*512 + col) =
            make_float4(acc[i][0], acc[i][1], acc[i][2], acc[i][3]);
    }
}

// in-place expmap0 over fp32 rows (rows x 512), store ome
__global__ __launch_bounds__(128)
void k_expmap(float* __restrict__ X, float* __restrict__ omeout)
{
    __shared__ float red[128];
    int row = blockIdx.x, t = threadIdx.x;
    float4 u = *(float4*)(X + (long long)row*512 + t*4);
    red[t] = u.x*u.x + u.y*u.y + u.z*u.z + u.w*u.w; __syncthreads();
    for (int s = 64; s > 0; s >>= 1){ if (t < s) red[t] += red[t+s]; __syncthreads(); }
    float f, ome;
    expmap_scale_ome(red[0], &f, &ome);
    *(float4*)(X + (long long)row*512 + t*4) = make_float4(u.x*f, u.y*f, u.z*f, u.w*f);
    if (t == 0) omeout[row] = ome;
}

// per doc-word row: 22 dots vs doc/sum/cand embeddings -> 1/pdist
__global__ __launch_bounds__(64)
void k_dots(const float* __restrict__ dwe, const float* __restrict__ dwe_ome,
            const float* __restrict__ doc_emb, const float* __restrict__ doc_ome,
            const float* __restrict__ sum_emb, const float* __restrict__ sum_ome,
            const float* __restrict__ cand_emb, const float* __restrict__ cand_ome,
            float* __restrict__ doc_inter, float* __restrict__ sum_inter,
            float* __restrict__ cand_inter)
{
    int row = blockIdx.x;            // b*1019 + l
    int b = row / 1019;
    int l = row - b*1019;
    int lane = threadIdx.x;
    const float* xr = dwe + (long long)row*512;
    float4 x0 = *(const float4*)(xr + lane*4);
    float4 x1 = *(const float4*)(xr + 256 + lane*4);
    float ox = dwe_ome[row];
    for (int c = 0; c < 22; c++){
        const float* y; float oy;
        if (c == 0){ y = doc_emb + b*512; oy = doc_ome[b]; }
        else if (c == 1){ y = sum_emb + b*512; oy = sum_ome[b]; }
        else { int cc = c - 2; y = cand_emb + (b*20 + cc)*512; oy = cand_ome[b*20 + cc]; }
        float4 y0 = *(const float4*)(y + lane*4);
        float4 y1v = *(const float4*)(y + 256 + lane*4);
        float s = x0.x*y0.x + x0.y*y0.y + x0.z*y0.z + x0.w*y0.w
                + x1.x*y1v.x + x1.y*y1v.y + x1.z*y1v.z + x1.w*y1v.w;
        for (int off = 32; off > 0; off >>= 1) s += __shfl_xor(s, off, 64);
        float dist = pdist_stable(ox, oy, s);
        if (lane == 0){
            float inv = 1.0f/fmaxf(dist, 1e-12f);
            if (c == 0) doc_inter[row] = inv;
            else if (c == 1) sum_inter[row] = inv;
            else cand_inter[((long long)(b*20 + (c-2)))*1019 + l] = inv;
        }
    }
}

// final: blocks 0..79 -> score[b,c]; 80..83 -> summary_score[b]; fp32 out
__global__ __launch_bounds__(256)
void k_final(const float* __restrict__ doc_inter, const float* __restrict__ sum_inter,
             const float* __restrict__ cand_inter,
             const float* __restrict__ doc_emb, const float* __restrict__ doc_ome,
             const float* __restrict__ sum_emb, const float* __restrict__ sum_ome,
             const float* __restrict__ cand_emb, const float* __restrict__ cand_ome,
             float* __restrict__ out)
{
    __shared__ float r0[256], r1[256], r2[256], r3[256];
    int j = blockIdx.x, t = threadIdx.x;
    int b; const float *a, *bb, *xe, *ye;
    float ox, oy; int outIdx;
    if (j < 80){
        b = j/20;
        a  = doc_inter + b*1019;
        bb = cand_inter + (long long)j*1019;
        xe = cand_emb + j*512; ox = cand_ome[j];
        ye = doc_emb + b*512;  oy = doc_ome[b];
        outIdx = j;
    } else {
        b = j - 80;
        a  = doc_inter + b*1019;
        bb = sum_inter + b*1019;
        xe = sum_emb + b*512;  ox = sum_ome[b];
        ye = doc_emb + b*512;  oy = doc_ome[b];
        outIdx = 80 + b;
    }
    float saa = 0.f, sbb = 0.f, sab = 0.f, st = 0.f;
    for (int l = t; l < 1019; l += 256){ float av = a[l], bv = bb[l]; saa += av*av; sbb += bv*bv; sab += av*bv; }
    for (int k = t; k < 512; k += 256) st += xe[k]*ye[k];
    r0[t] = saa; r1[t] = sbb; r2[t] = sab; r3[t] = st; __syncthreads();
    for (int s = 128; s > 0; s >>= 1){
        if (t < s){ r0[t] += r0[t+s]; r1[t] += r1[t+s]; r2[t] += r2[t+s]; r3[t] += r3[t+s]; }
        __syncthreads();
    }
    if (t == 0){
        float na = fmaxf(sqrtf(r0[0]), 1e-8f);
        float nb = fmaxf(sqrtf(r1[0]), 1e-8f);
        float cosv = r2[0] / (na*nb);
        float pd = pdist_stable(ox, oy, r3[0]);
        out[outIdx] = -pd*pd + cosv;
    }
}

extern "C" void kernel_launch(void* const* d_in, const int* in_sizes, int n_in,
                              void* d_out, int out_size, void* d_ws, size_t ws_size,
                              hipStream_t stream) {
    const float* text = (const float*)d_in[0];   // (4,512,768) fp32
    const float* summ = (const float*)d_in[1];   // (4,128,768)
    const float* cand = (const float*)d_in[2];   // (4,20,128,768)
    const float* W_d  = (const float*)d_in[3];   // (768,512)
    const float* W_s  = (const float*)d_in[4];
    const float* W_c  = (const float*)d_in[5];
    const float* W_p  = (const float*)d_in[6];   // (512,512)
    const float* cw1  = (const float*)d_in[7];   // (1,768,512)
    const float* cb1  = (const float*)d_in[8];   // (512,)
    const float* cw2  = (const float*)d_in[9];   // (2,768,512) = (1536,512)
    const float* cb2  = (const float*)d_in[10];  // (512,)
    float* out = (float*)d_out;                  // 84 fp32

    const int B = 4, C = 20, H = 768;

    char* base = (char*)d_ws;
    size_t off = 0;
    auto allocF = [&](size_t n)->float*{ float* p = (float*)(base + off); off += ((n*4) + 255) & ~(size_t)255; return p; };

    float* smax = allocF(B*H);
    float* cmax = allocF(B*C*H);
    float* doc_emb  = allocF(B*512);   float* doc_ome  = allocF(B);
    float* sum_emb  = allocF(B*512);   float* sum_ome  = allocF(B);
    float* cand_emb = allocF(B*C*512); float* cand_ome = allocF(B*C);
    float* gram = allocF(4076*512);
    float* dwe  = allocF(4076*512);
    float* dwe_ome   = allocF(4076);
    float* doc_inter = allocF(4076);
    float* sum_inter = allocF(4076);
    float* cand_inter= allocF(B*C*1019);

    // 1. merged max-reductions (summary + candidate)
    k_rowmax_all<<<(84*H + 255)/256, 256, 0, stream>>>(summ, cand, smax, cmax);

    // 2. merged embedding rows (doc + sum + cand)
    k_emb_all<<<88, 256, 0, stream>>>(text, smax, cmax, W_d, W_s, W_c,
                                      doc_emb, doc_ome, sum_emb, sum_ome, cand_emb, cand_ome);

    // 3. merged conv GEMMs (conv1 K=768 + conv2 K=1536 interleaved), 512 blocks
    dim3 gconv(64, 8);
    k_conv<<<gconv, 256, 0, stream>>>(text, cw1, cb1, cw2, cb2, gram);

    // 4. W_p GEMM, 512 blocks, then expmap0 rows
    dim3 gwp(64, 8);
    k_wp<<<gwp, 256, 0, stream>>>(gram, W_p, dwe);
    k_expmap<<<4076, 128, 0, stream>>>(dwe, dwe_ome);

    // 5. all pairwise dots -> 1/pdist
    k_dots<<<4076, 64, 0, stream>>>(dwe, dwe_ome, doc_emb, doc_ome, sum_emb, sum_ome,
                                    cand_emb, cand_ome, doc_inter, sum_inter, cand_inter);

    // 6. cos_sim reductions + pair pdist -> fp32 outputs
    k_final<<<84, 256, 0, stream>>>(doc_inter, sum_inter, cand_inter,
                                    doc_emb, doc_ome, sum_emb, sum_ome,
                                    cand_emb, cand_ome, out);
}

// Round 5
// 258.815 us; speedup vs baseline: 1.9194x; 1.3204x over previous
//
#include <hip/hip_runtime.h>
#include <math.h>

#define SQRTC  0.94868329805051381f       // sqrt(0.9)
#define MAXN   (0.996f/SQRTC)             // (1-PROJ_EPS)/sqrt(c)
#define OME_CLIP (1.0f - 0.996f*0.996f)   // 1 - c*maxnorm^2
#define TWO_OVER_SQRTC 2.1081851067789197f

typedef unsigned short u16;
typedef __attribute__((ext_vector_type(8))) short bf8;   // 8 bf16 (4 VGPRs)
typedef __attribute__((ext_vector_type(4))) float f4;    // MFMA C/D

__device__ __forceinline__ u16 f2bf(float f){
    union { float f; unsigned int i; } v; v.f = f;
    unsigned int x = v.i;
    unsigned int lsb = (x >> 16) & 1u;
    x += 0x7fffu + lsb;
    return (u16)(x >> 16);
}

// stable pdist from ome_x = 1-c*||x||^2, ome_y = 1-c*||y||^2, t = dot(x,y)
__device__ __forceinline__ float pdist_stable(float ome_x, float ome_y, float t){
    float u = 1.0f - ome_x, v = 1.0f - ome_y;   // c*x2, c*y2
    float den = fmaxf(1.0f - 1.8f*t + u*v, 1e-15f);
    float q = ome_x*ome_y/den;                   // = 1 - z^2
    q = fminf(fmaxf(q, 2.0e-7f), 1.0f);
    float z = sqrtf(fmaxf(1.0f - q, 0.0f));
    float at = 0.5f * logf((1.0f+z)*(1.0f+z)/q); // atanh(z)
    return TWO_OVER_SQRTC * at;
}

__device__ __forceinline__ void expmap_scale_ome(float sum, float* fout, float* omeout){
    float nraw = sqrtf(fmaxf(sum, 1e-30f));
    float n = fmaxf(nraw, 1e-15f);
    float sn = SQRTC*n;
    float th = tanhf(sn);
    float factor = th/sn;
    float gn = factor*nraw;
    if (gn > MAXN){ *fout = factor*(MAXN/gn); *omeout = OME_CLIP; }
    else { *fout = factor; *omeout = fmaxf((1.0f-th)*(1.0f+th), 1e-12f); }
}

// merged max-reductions: summary (4 rows) then cand (80 rows), red=128, H=768
__global__ void k_rowmax_all(const float* __restrict__ summ, const float* __restrict__ cand,
                             float* __restrict__ smax, float* __restrict__ cmax)
{
    int idx = blockIdx.x*256 + threadIdx.x;
    const int H = 768;
    if (idx < 4*H){
        int row = idx / H, h = idx - row*H;
        const float* p = summ + (long long)row*128*H + h;
        float m = -INFINITY;
        for (int l = 0; l < 128; l++) m = fmaxf(m, p[l*H]);
        smax[idx] = m;
    } else {
        int i2 = idx - 4*H;
        if (i2 >= 80*H) return;
        int row = i2 / H, h = i2 - row*H;
        const float* p = cand + (long long)row*128*H + h;
        float m = -INFINITY;
        for (int l = 0; l < 128; l++) m = fmaxf(m, p[l*H]);
        cmax[i2] = m;
    }
}

// pre-pass: convert text -> bf16 (row-major, k-contig) and transpose+convert the
// three weight matrices to [n][k] bf16 so MFMA staging is pure b128 copies.
// blocks 0..767: text cvt (2048 elems each). 768..1151: w1 (24x16 tiles).
// 1152..1919: w2 (48x16). 1920..2175: wp (16x16).
__global__ __launch_bounds__(256)
void k_prep(const float* __restrict__ text, const float* __restrict__ w1,
            const float* __restrict__ w2, const float* __restrict__ wp,
            u16* __restrict__ textb, u16* __restrict__ w1t,
            u16* __restrict__ w2t, u16* __restrict__ wpt)
{
    __shared__ float tile[32][33];
    int bx = blockIdx.x;
    if (bx < 768){
        int base = bx*2048 + threadIdx.x*8;
        float4 a = *(const float4*)(text + base);
        float4 b = *(const float4*)(text + base + 4);
        ushort4 o0 = make_ushort4(f2bf(a.x), f2bf(a.y), f2bf(a.z), f2bf(a.w));
        ushort4 o1 = make_ushort4(f2bf(b.x), f2bf(b.y), f2bf(b.z), f2bf(b.w));
        *(ushort4*)(textb + base)     = o0;
        *(ushort4*)(textb + base + 4) = o1;
        return;
    }
    int j = bx - 768;
    const float* in; u16* outp; int K;
    if (j < 384){ in = w1; outp = w1t; K = 768; }
    else if (j < 1152){ j -= 384; in = w2; outp = w2t; K = 1536; }
    else { j -= 1152; in = wp; outp = wpt; K = 512; }
    const int N = 512, ntile = N/32;
    int k0 = (j/ntile)*32, n0 = (j - (j/ntile)*ntile)*32;
    int tx = threadIdx.x & 31, ty = threadIdx.x >> 5;   // ty 0..7
    #pragma unroll
    for (int i = 0; i < 4; i++)
        tile[ty*4+i][tx] = in[(long long)(k0 + ty*4 + i)*N + n0 + tx];
    __syncthreads();
    #pragma unroll
    for (int i = 0; i < 4; i++)
        outp[(long long)(n0 + ty*4 + i)*K + k0 + tx] = f2bf(tile[tx][ty*4+i]);
}

// merged embedding rows: grid 88. 0..3 doc, 4..7 sum, 8..87 cand (fp32 GEMV)
__global__ __launch_bounds__(256)
void k_emb_all(const float* __restrict__ text,
               const float* __restrict__ smaxv, const float* __restrict__ cmaxv,
               const float* __restrict__ W_d, const float* __restrict__ W_s, const float* __restrict__ W_c,
               float* __restrict__ doc_emb, float* __restrict__ doc_ome,
               float* __restrict__ sum_emb, float* __restrict__ sum_ome,
               float* __restrict__ cand_emb, float* __restrict__ cand_ome)
{
    __shared__ float a[768];
    __shared__ float red[256];
    int row = blockIdx.x, t = threadIdx.x;
    const float* A; const float* W; float* emb; float* ome;
    if (row < 4){ A = text + (long long)row*512*768; W = W_d; emb = doc_emb + row*512; ome = doc_ome + row; }
    else if (row < 8){ int r = row-4; A = smaxv + r*768; W = W_s; emb = sum_emb + r*512; ome = sum_ome + r; }
    else { int r = row-8; A = cmaxv + r*768; W = W_c; emb = cand_emb + r*512; ome = cand_ome + r; }
    for (int k = t; k < 768; k += 256) a[k] = A[k];
    __syncthreads();
    float acc0 = 0.f, acc1 = 0.f;
    #pragma unroll 4
    for (int k = 0; k < 768; k++){
        float av = a[k];
        acc0 += av * W[k*512 + t];
        acc1 += av * W[k*512 + t + 256];
    }
    red[t] = acc0*acc0 + acc1*acc1; __syncthreads();
    for (int s = 128; s > 0; s >>= 1){ if (t < s) red[t] += red[t+s]; __syncthreads(); }
    float f, omev;
    expmap_scale_ome(red[0], &f, &omev);
    emb[t]       = acc0*f;
    emb[t + 256] = acc1*f;
    if (t == 0) *ome = omev;
}

// MFMA conv GEMM: blockIdx.x even -> conv1 (K=768), odd -> conv2 (K=1536).
// BM=64 BN=64 BK=32; 4 waves, each wave owns 16 rows x 64 cols (4 mfma tiles).
// Epilogue: bias+relu, emit gram as bf16.
__global__ __launch_bounds__(256)
void k_conv_mfma(const u16* __restrict__ textb,
                 const u16* __restrict__ w1t, const u16* __restrict__ w2t,
                 const float* __restrict__ cb1, const float* __restrict__ cb2,
                 u16* __restrict__ gram)
{
    __shared__ u16 As[64][32];   // [m][k]
    __shared__ u16 Bs[64][32];   // [n][k]
    int job = blockIdx.x & 1;
    int m0 = (blockIdx.x >> 1) * 64;
    int n0 = blockIdx.y * 64;
    int K   = job ? 1536 : 768;
    int M   = job ? 2036 : 2040;
    int rpb = job ? 509 : 510;
    int ob  = job ? 510 : 0;
    const u16* Bt = job ? w2t : w1t;
    const float* bias = job ? cb2 : cb1;
    int t = threadIdx.x;
    int sr = t >> 2, sk = (t & 3) << 3;   // staging: row 0..63, k-off {0,8,16,24}
    const u16* Arow = nullptr;
    { int gm = m0 + sr; if (gm < M){ int b = gm/rpb, l = gm - b*rpb;
        Arow = textb + (long long)b*393216 + (long long)(l+1)*768; } }
    const u16* Brow = Bt + (long long)(n0 + sr)*K;
    int lane = t & 63, wv = t >> 6;
    int fm = lane & 15, fq = lane >> 4;
    int arow = wv*16 + fm;
    f4 acc0 = {0,0,0,0}, acc1 = {0,0,0,0}, acc2 = {0,0,0,0}, acc3 = {0,0,0,0};
    for (int k0 = 0; k0 < K; k0 += 32){
        bf8 av = {};
        if (Arow) av = *(const bf8*)(Arow + k0 + sk);
        bf8 bv = *(const bf8*)(Brow + k0 + sk);
        *(bf8*)&As[sr][sk] = av;
        *(bf8*)&Bs[sr][sk] = bv;
        __syncthreads();
        bf8 af = *(const bf8*)&As[arow][fq*8];
        bf8 b0 = *(const bf8*)&Bs[ 0+fm][fq*8];
        bf8 b1 = *(const bf8*)&Bs[16+fm][fq*8];
        bf8 b2 = *(const bf8*)&Bs[32+fm][fq*8];
        bf8 b3 = *(const bf8*)&Bs[48+fm][fq*8];
        acc0 = __builtin_amdgcn_mfma_f32_16x16x32_bf16(af, b0, acc0, 0, 0, 0);
        acc1 = __builtin_amdgcn_mfma_f32_16x16x32_bf16(af, b1, acc1, 0, 0, 0);
        acc2 = __builtin_amdgcn_mfma_f32_16x16x32_bf16(af, b2, acc2, 0, 0, 0);
        acc3 = __builtin_amdgcn_mfma_f32_16x16x32_bf16(af, b3, acc3, 0, 0, 0);
        __syncthreads();
    }
    int col = n0 + fm;
    float bv0 = bias[col], bv1 = bias[col+16], bv2 = bias[col+32], bv3 = bias[col+48];
    #pragma unroll
    for (int i = 0; i < 4; i++){
        int row = m0 + wv*16 + fq*4 + i;
        if (row >= M) continue;
        int b = row/rpb, l = row - b*rpb;
        long long orow = (long long)b*1019 + ob + l;
        u16* gp = gram + orow*512;
        gp[col]      = f2bf(fmaxf(acc0[i] + bv0, 0.f));
        gp[col + 16] = f2bf(fmaxf(acc1[i] + bv1, 0.f));
        gp[col + 32] = f2bf(fmaxf(acc2[i] + bv2, 0.f));
        gp[col + 48] = f2bf(fmaxf(acc3[i] + bv3, 0.f));
    }
}

// MFMA W_p GEMM: dwe(4076x512 fp32) = gram(bf16) @ W_p (via wpt [n][k] bf16)
__global__ __launch_bounds__(256)
void k_wp_mfma(const u16* __restrict__ gram, const u16* __restrict__ wpt,
               float* __restrict__ dwe)
{
    __shared__ u16 As[64][32];
    __shared__ u16 Bs[64][32];
    const int K = 512, M = 4076;
    int m0 = blockIdx.x * 64;
    int n0 = blockIdx.y * 64;
    int t = threadIdx.x;
    int sr = t >> 2, sk = (t & 3) << 3;
    const u16* Arow = (m0 + sr < M) ? (gram + (long long)(m0 + sr)*512) : nullptr;
    const u16* Brow = wpt + (long long)(n0 + sr)*K;
    int lane = t & 63, wv = t >> 6;
    int fm = lane & 15, fq = lane >> 4;
    int arow = wv*16 + fm;
    f4 acc0 = {0,0,0,0}, acc1 = {0,0,0,0}, acc2 = {0,0,0,0}, acc3 = {0,0,0,0};
    for (int k0 = 0; k0 < K; k0 += 32){
        bf8 av = {};
        if (Arow) av = *(const bf8*)(Arow + k0 + sk);
        bf8 bv = *(const bf8*)(Brow + k0 + sk);
        *(bf8*)&As[sr][sk] = av;
        *(bf8*)&Bs[sr][sk] = bv;
        __syncthreads();
        bf8 af = *(const bf8*)&As[arow][fq*8];
        bf8 b0 = *(const bf8*)&Bs[ 0+fm][fq*8];
        bf8 b1 = *(const bf8*)&Bs[16+fm][fq*8];
        bf8 b2 = *(const bf8*)&Bs[32+fm][fq*8];
        bf8 b3 = *(const bf8*)&Bs[48+fm][fq*8];
        acc0 = __builtin_amdgcn_mfma_f32_16x16x32_bf16(af, b0, acc0, 0, 0, 0);
        acc1 = __builtin_amdgcn_mfma_f32_16x16x32_bf16(af, b1, acc1, 0, 0, 0);
        acc2 = __builtin_amdgcn_mfma_f32_16x16x32_bf16(af, b2, acc2, 0, 0, 0);
        acc3 = __builtin_amdgcn_mfma_f32_16x16x32_bf16(af, b3, acc3, 0, 0, 0);
        __syncthreads();
    }
    int col = n0 + fm;
    #pragma unroll
    for (int i = 0; i < 4; i++){
        int row = m0 + wv*16 + fq*4 + i;
        if (row >= M) continue;
        float* dp = dwe + (long long)row*512;
        dp[col]      = acc0[i];
        dp[col + 16] = acc1[i];
        dp[col + 32] = acc2[i];
        dp[col + 48] = acc3[i];
    }
}

// in-place expmap0 over fp32 rows (rows x 512), store ome
__global__ __launch_bounds__(128)
void k_expmap(float* __restrict__ X, float* __restrict__ omeout)
{
    __shared__ float red[128];
    int row = blockIdx.x, t = threadIdx.x;
    float4 u = *(float4*)(X + (long long)row*512 + t*4);
    red[t] = u.x*u.x + u.y*u.y + u.z*u.z + u.w*u.w; __syncthreads();
    for (int s = 64; s > 0; s >>= 1){ if (t < s) red[t] += red[t+s]; __syncthreads(); }
    float f, ome;
    expmap_scale_ome(red[0], &f, &ome);
    *(float4*)(X + (long long)row*512 + t*4) = make_float4(u.x*f, u.y*f, u.z*f, u.w*f);
    if (t == 0) omeout[row] = ome;
}

// per doc-word row: 22 dots vs doc/sum/cand embeddings -> 1/pdist
__global__ __launch_bounds__(64)
void k_dots(const float* __restrict__ dwe, const float* __restrict__ dwe_ome,
            const float* __restrict__ doc_emb, const float* __restrict__ doc_ome,
            const float* __restrict__ sum_emb, const float* __restrict__ sum_ome,
            const float* __restrict__ cand_emb, const float* __restrict__ cand_ome,
            float* __restrict__ doc_inter, float* __restrict__ sum_inter,
            float* __restrict__ cand_inter)
{
    int row = blockIdx.x;            // b*1019 + l
    int b = row / 1019;
    int l = row - b*1019;
    int lane = threadIdx.x;
    const float* xr = dwe + (long long)row*512;
    float4 x0 = *(const float4*)(xr + lane*4);
    float4 x1 = *(const float4*)(xr + 256 + lane*4);
    float ox = dwe_ome[row];
    for (int c = 0; c < 22; c++){
        const float* y; float oy;
        if (c == 0){ y = doc_emb + b*512; oy = doc_ome[b]; }
        else if (c == 1){ y = sum_emb + b*512; oy = sum_ome[b]; }
        else { int cc = c - 2; y = cand_emb + (b*20 + cc)*512; oy = cand_ome[b*20 + cc]; }
        float4 y0 = *(const float4*)(y + lane*4);
        float4 y1v = *(const float4*)(y + 256 + lane*4);
        float s = x0.x*y0.x + x0.y*y0.y + x0.z*y0.z + x0.w*y0.w
                + x1.x*y1v.x + x1.y*y1v.y + x1.z*y1v.z + x1.w*y1v.w;
        for (int off = 32; off > 0; off >>= 1) s += __shfl_xor(s, off, 64);
        float dist = pdist_stable(ox, oy, s);
        if (lane == 0){
            float inv = 1.0f/fmaxf(dist, 1e-12f);
            if (c == 0) doc_inter[row] = inv;
            else if (c == 1) sum_inter[row] = inv;
            else cand_inter[((long long)(b*20 + (c-2)))*1019 + l] = inv;
        }
    }
}

// final: blocks 0..79 -> score[b,c]; 80..83 -> summary_score[b]; fp32 out
__global__ __launch_bounds__(256)
void k_final(const float* __restrict__ doc_inter, const float* __restrict__ sum_inter,
             const float* __restrict__ cand_inter,
             const float* __restrict__ doc_emb, const float* __restrict__ doc_ome,
             const float* __restrict__ sum_emb, const float* __restrict__ sum_ome,
             const float* __restrict__ cand_emb, const float* __restrict__ cand_ome,
             float* __restrict__ out)
{
    __shared__ float r0[256], r1[256], r2[256], r3[256];
    int j = blockIdx.x, t = threadIdx.x;
    int b; const float *a, *bb, *xe, *ye;
    float ox, oy; int outIdx;
    if (j < 80){
        b = j/20;
        a  = doc_inter + b*1019;
        bb = cand_inter + (long long)j*1019;
        xe = cand_emb + j*512; ox = cand_ome[j];
        ye = doc_emb + b*512;  oy = doc_ome[b];
        outIdx = j;
    } else {
        b = j - 80;
        a  = doc_inter + b*1019;
        bb = sum_inter + b*1019;
        xe = sum_emb + b*512;  ox = sum_ome[b];
        ye = doc_emb + b*512;  oy = doc_ome[b];
        outIdx = 80 + b;
    }
    float saa = 0.f, sbb = 0.f, sab = 0.f, st = 0.f;
    for (int l = t; l < 1019; l += 256){ float av = a[l], bv = bb[l]; saa += av*av; sbb += bv*bv; sab += av*bv; }
    for (int k = t; k < 512; k += 256) st += xe[k]*ye[k];
    r0[t] = saa; r1[t] = sbb; r2[t] = sab; r3[t] = st; __syncthreads();
    for (int s = 128; s > 0; s >>= 1){
        if (t < s){ r0[t] += r0[t+s]; r1[t] += r1[t+s]; r2[t] += r2[t+s]; r3[t] += r3[t+s]; }
        __syncthreads();
    }
    if (t == 0){
        float na = fmaxf(sqrtf(r0[0]), 1e-8f);
        float nb = fmaxf(sqrtf(r1[0]), 1e-8f);
        float cosv = r2[0] / (na*nb);
        float pd = pdist_stable(ox, oy, r3[0]);
        out[outIdx] = -pd*pd + cosv;
    }
}

extern "C" void kernel_launch(void* const* d_in, const int* in_sizes, int n_in,
                              void* d_out, int out_size, void* d_ws, size_t ws_size,
                              hipStream_t stream) {
    const float* text = (const float*)d_in[0];   // (4,512,768) fp32
    const float* summ = (const float*)d_in[1];   // (4,128,768)
    const float* cand = (const float*)d_in[2];   // (4,20,128,768)
    const float* W_d  = (const float*)d_in[3];   // (768,512)
    const float* W_s  = (const float*)d_in[4];
    const float* W_c  = (const float*)d_in[5];
    const float* W_p  = (const float*)d_in[6];   // (512,512)
    const float* cw1  = (const float*)d_in[7];   // (1,768,512)
    const float* cb1  = (const float*)d_in[8];   // (512,)
    const float* cw2  = (const float*)d_in[9];   // (2,768,512) = (1536,512)
    const float* cb2  = (const float*)d_in[10];  // (512,)
    float* out = (float*)d_out;                  // 84 fp32

    const int B = 4, C = 20, H = 768;

    char* base = (char*)d_ws;
    size_t off = 0;
    auto allocF = [&](size_t n)->float*{ float* p = (float*)(base + off); off += ((n*4) + 255) & ~(size_t)255; return p; };
    auto allocU = [&](size_t n)->u16*{ u16* p = (u16*)(base + off); off += ((n*2) + 255) & ~(size_t)255; return p; };

    float* smax = allocF(B*H);
    float* cmax = allocF(B*C*H);
    float* doc_emb  = allocF(B*512);   float* doc_ome  = allocF(B);
    float* sum_emb  = allocF(B*512);   float* sum_ome  = allocF(B);
    float* cand_emb = allocF(B*C*512); float* cand_ome = allocF(B*C);
    u16* textb = allocU(4*512*768);    // bf16 text
    u16* w1t   = allocU(512*768);      // w1^T  [n][k]
    u16* w2t   = allocU(512*1536);     // w2^T  [n][k]
    u16* wpt   = allocU(512*512);      // W_p^T [n][k]
    u16* gram  = allocU(4076*512);     // bf16 gram
    float* dwe = allocF(4076*512);     // fp32 doc_word emb
    float* dwe_ome   = allocF(4076);
    float* doc_inter = allocF(4076);
    float* sum_inter = allocF(4076);
    float* cand_inter= allocF(B*C*1019);
    // ~19.2 MB

    // 1. merged max-reductions (independent of prep)
    k_rowmax_all<<<(84*H + 255)/256, 256, 0, stream>>>(summ, cand, smax, cmax);

    // 2. pre-pass: bf16 convert text + transpose/convert weights
    k_prep<<<2176, 256, 0, stream>>>(text, cw1, cw2, W_p, textb, w1t, w2t, wpt);

    // 3. merged embedding rows (fp32 GEMV, independent)
    k_emb_all<<<88, 256, 0, stream>>>(text, smax, cmax, W_d, W_s, W_c,
                                      doc_emb, doc_ome, sum_emb, sum_ome, cand_emb, cand_ome);

    // 4. MFMA conv GEMMs (conv1 + conv2 interleaved) -> gram bf16
    dim3 gconv(64, 8);
    k_conv_mfma<<<gconv, 256, 0, stream>>>(textb, w1t, w2t, cb1, cb2, gram);

    // 5. MFMA W_p GEMM -> dwe fp32, then expmap0 rows
    dim3 gwp(64, 8);
    k_wp_mfma<<<gwp, 256, 0, stream>>>(gram, wpt, dwe);
    k_expmap<<<4076, 128, 0, stream>>>(dwe, dwe_ome);

    // 6. all pairwise dots -> 1/pdist
    k_dots<<<4076, 64, 0, stream>>>(dwe, dwe_ome, doc_emb, doc_ome, sum_emb, sum_ome,
                                    cand_emb, cand_ome, doc_inter, sum_inter, cand_inter);

    // 7. cos_sim reductions + pair pdist -> fp32 outputs
    k_final<<<84, 256, 0, stream>>>(doc_inter, sum_inter, cand_inter,
                                    doc_emb, doc_ome, sum_emb, sum_ome,
                                    cand_emb, cand_ome, out);
}

// Round 6
// 179.116 us; speedup vs baseline: 2.7734x; 1.4450x over previous
//
#include <hip/hip_runtime.h>
#include <math.h>

#define SQRTC  0.94868329805051381f       // sqrt(0.9)
#define MAXN   (0.996f/SQRTC)             // (1-PROJ_EPS)/sqrt(c)
#define OME_CLIP (1.0f - 0.996f*0.996f)   // 1 - c*maxnorm^2
#define TWO_OVER_SQRTC 2.1081851067789197f

typedef unsigned short u16;
typedef __attribute__((ext_vector_type(8))) short bf8;   // 8 bf16 (4 VGPRs)
typedef __attribute__((ext_vector_type(4))) float f4;    // MFMA C/D

__device__ __forceinline__ u16 f2bf(float f){
    union { float f; unsigned int i; } v; v.f = f;
    unsigned int x = v.i;
    unsigned int lsb = (x >> 16) & 1u;
    x += 0x7fffu + lsb;
    return (u16)(x >> 16);
}

__device__ __forceinline__ float pdist_stable(float ome_x, float ome_y, float t){
    float u = 1.0f - ome_x, v = 1.0f - ome_y;   // c*x2, c*y2
    float den = fmaxf(1.0f - 1.8f*t + u*v, 1e-15f);
    float q = ome_x*ome_y/den;                   // = 1 - z^2
    q = fminf(fmaxf(q, 2.0e-7f), 1.0f);
    float z = sqrtf(fmaxf(1.0f - q, 0.0f));
    float at = 0.5f * logf((1.0f+z)*(1.0f+z)/q); // atanh(z)
    return TWO_OVER_SQRTC * at;
}

__device__ __forceinline__ void expmap_scale_ome(float sum, float* fout, float* omeout){
    float nraw = sqrtf(fmaxf(sum, 1e-30f));
    float n = fmaxf(nraw, 1e-15f);
    float sn = SQRTC*n;
    float th = tanhf(sn);
    float factor = th/sn;
    float gn = factor*nraw;
    if (gn > MAXN){ *fout = factor*(MAXN/gn); *omeout = OME_CLIP; }
    else { *fout = factor; *omeout = fmaxf((1.0f-th)*(1.0f+th), 1e-12f); }
}

// max over l=128: 84 rows (4 summ + 80 cand), 12 h-tiles of 64, 4 l-groups of 32
__global__ __launch_bounds__(256)
void k_rowmax2(const float* __restrict__ summ, const float* __restrict__ cand,
               float* __restrict__ smax, float* __restrict__ cmax)
{
    __shared__ float red[256];
    int bx = blockIdx.x;
    int row = bx / 12, ht = bx - row*12;
    int t = threadIdx.x, lane = t & 63, lg = t >> 6;
    int h = ht*64 + lane;
    const float* in = (row < 4) ? (summ + (long long)row*128*768)
                                : (cand + (long long)(row-4)*128*768);
    const float* p = in + (long long)(lg*32)*768 + h;
    float m = -INFINITY;
    #pragma unroll 8
    for (int l = 0; l < 32; l++) m = fmaxf(m, p[l*768]);
    red[t] = m; __syncthreads();
    if (t < 64){
        float mm = fmaxf(fmaxf(red[t], red[t+64]), fmaxf(red[t+128], red[t+192]));
        if (row < 4) smax[row*768 + h] = mm;
        else cmax[(row-4)*768 + h] = mm;
    }
}

// pre-pass: text -> bf16; weights -> [n][k] bf16 transposes
__global__ __launch_bounds__(256)
void k_prep(const float* __restrict__ text, const float* __restrict__ w1,
            const float* __restrict__ w2, const float* __restrict__ wp,
            u16* __restrict__ textb, u16* __restrict__ w1t,
            u16* __restrict__ w2t, u16* __restrict__ wpt)
{
    __shared__ float tile[32][33];
    int bx = blockIdx.x;
    if (bx < 768){
        int base = bx*2048 + threadIdx.x*8;
        float4 a = *(const float4*)(text + base);
        float4 b = *(const float4*)(text + base + 4);
        ushort4 o0 = make_ushort4(f2bf(a.x), f2bf(a.y), f2bf(a.z), f2bf(a.w));
        ushort4 o1 = make_ushort4(f2bf(b.x), f2bf(b.y), f2bf(b.z), f2bf(b.w));
        *(ushort4*)(textb + base)     = o0;
        *(ushort4*)(textb + base + 4) = o1;
        return;
    }
    int j = bx - 768;
    const float* in; u16* outp; int K;
    if (j < 384){ in = w1; outp = w1t; K = 768; }
    else if (j < 1152){ j -= 384; in = w2; outp = w2t; K = 1536; }
    else { j -= 1152; in = wp; outp = wpt; K = 512; }
    const int N = 512, ntile = N/32;
    int k0 = (j/ntile)*32, n0 = (j - (j/ntile)*ntile)*32;
    int tx = threadIdx.x & 31, ty = threadIdx.x >> 5;   // ty 0..7
    #pragma unroll
    for (int i = 0; i < 4; i++)
        tile[ty*4+i][tx] = in[(long long)(k0 + ty*4 + i)*N + n0 + tx];
    __syncthreads();
    #pragma unroll
    for (int i = 0; i < 4; i++)
        outp[(long long)(n0 + ty*4 + i)*K + k0 + tx] = f2bf(tile[tx][ty*4+i]);
}

// embedding GEMV, split: 88 rows x 8 col-tiles = 704 blocks.
// threads: 64 lanes (cols) x 4 k-groups of 192. Raw output -> emb_all (scaled later).
__global__ __launch_bounds__(256)
void k_emb_gemv(const float* __restrict__ text,
                const float* __restrict__ smaxv, const float* __restrict__ cmaxv,
                const float* __restrict__ W_d, const float* __restrict__ W_s, const float* __restrict__ W_c,
                float* __restrict__ emb_all)
{
    __shared__ float a[768];
    __shared__ float red[256];
    int bx = blockIdx.x;
    int row = bx >> 3, nt = bx & 7;
    int t = threadIdx.x;
    const float* A; const float* W;
    if (row < 4){ A = text + (long long)row*512*768; W = W_d; }       // text[:,0,:]
    else if (row < 8){ A = smaxv + (long long)(row-4)*768; W = W_s; }
    else { A = cmaxv + (long long)(row-8)*768; W = W_c; }
    for (int k = t; k < 768; k += 256) a[k] = A[k];
    __syncthreads();
    int lane = t & 63, kg = t >> 6;
    int col = nt*64 + lane;
    const float* Wp = W + (long long)(kg*192)*512 + col;
    float acc = 0.f;
    #pragma unroll 8
    for (int k = 0; k < 192; k++) acc += a[kg*192 + k] * Wp[k*512];
    red[t] = acc; __syncthreads();
    if (t < 64){
        float s = red[t] + red[t+64] + red[t+128] + red[t+192];
        emb_all[(long long)row*512 + col] = s;
    }
}

// MFMA conv GEMM: blockIdx.x even -> conv1 (K=768), odd -> conv2 (K=1536).
__global__ __launch_bounds__(256)
void k_conv_mfma(const u16* __restrict__ textb,
                 const u16* __restrict__ w1t, const u16* __restrict__ w2t,
                 const float* __restrict__ cb1, const float* __restrict__ cb2,
                 u16* __restrict__ gram)
{
    __shared__ u16 As[64][32];   // [m][k]
    __shared__ u16 Bs[64][32];   // [n][k]
    int job = blockIdx.x & 1;
    int m0 = (blockIdx.x >> 1) * 64;
    int n0 = blockIdx.y * 64;
    int K   = job ? 1536 : 768;
    int M   = job ? 2036 : 2040;
    int rpb = job ? 509 : 510;
    int ob  = job ? 510 : 0;
    const u16* Bt = job ? w2t : w1t;
    const float* bias = job ? cb2 : cb1;
    int t = threadIdx.x;
    int sr = t >> 2, sk = (t & 3) << 3;
    const u16* Arow = nullptr;
    { int gm = m0 + sr; if (gm < M){ int b = gm/rpb, l = gm - b*rpb;
        Arow = textb + (long long)b*393216 + (long long)(l+1)*768; } }
    const u16* Brow = Bt + (long long)(n0 + sr)*K;
    int lane = t & 63, wv = t >> 6;
    int fm = lane & 15, fq = lane >> 4;
    int arow = wv*16 + fm;
    f4 acc0 = {0,0,0,0}, acc1 = {0,0,0,0}, acc2 = {0,0,0,0}, acc3 = {0,0,0,0};
    for (int k0 = 0; k0 < K; k0 += 32){
        bf8 av = {};
        if (Arow) av = *(const bf8*)(Arow + k0 + sk);
        bf8 bv = *(const bf8*)(Brow + k0 + sk);
        *(bf8*)&As[sr][sk] = av;
        *(bf8*)&Bs[sr][sk] = bv;
        __syncthreads();
        bf8 af = *(const bf8*)&As[arow][fq*8];
        bf8 b0 = *(const bf8*)&Bs[ 0+fm][fq*8];
        bf8 b1 = *(const bf8*)&Bs[16+fm][fq*8];
        bf8 b2 = *(const bf8*)&Bs[32+fm][fq*8];
        bf8 b3 = *(const bf8*)&Bs[48+fm][fq*8];
        acc0 = __builtin_amdgcn_mfma_f32_16x16x32_bf16(af, b0, acc0, 0, 0, 0);
        acc1 = __builtin_amdgcn_mfma_f32_16x16x32_bf16(af, b1, acc1, 0, 0, 0);
        acc2 = __builtin_amdgcn_mfma_f32_16x16x32_bf16(af, b2, acc2, 0, 0, 0);
        acc3 = __builtin_amdgcn_mfma_f32_16x16x32_bf16(af, b3, acc3, 0, 0, 0);
        __syncthreads();
    }
    int col = n0 + fm;
    float bv0 = bias[col], bv1 = bias[col+16], bv2 = bias[col+32], bv3 = bias[col+48];
    #pragma unroll
    for (int i = 0; i < 4; i++){
        int row = m0 + wv*16 + fq*4 + i;
        if (row >= M) continue;
        int b = row/rpb, l = row - b*rpb;
        long long orow = (long long)b*1019 + ob + l;
        u16* gp = gram + orow*512;
        gp[col]      = f2bf(fmaxf(acc0[i] + bv0, 0.f));
        gp[col + 16] = f2bf(fmaxf(acc1[i] + bv1, 0.f));
        gp[col + 32] = f2bf(fmaxf(acc2[i] + bv2, 0.f));
        gp[col + 48] = f2bf(fmaxf(acc3[i] + bv3, 0.f));
    }
}

// MFMA W_p GEMM: dwe(4076x512 fp32) = gram(bf16) @ W_p (wpt [n][k] bf16)
__global__ __launch_bounds__(256)
void k_wp_mfma(const u16* __restrict__ gram, const u16* __restrict__ wpt,
               float* __restrict__ dwe)
{
    __shared__ u16 As[64][32];
    __shared__ u16 Bs[64][32];
    const int K = 512, M = 4076;
    int m0 = blockIdx.x * 64;
    int n0 = blockIdx.y * 64;
    int t = threadIdx.x;
    int sr = t >> 2, sk = (t & 3) << 3;
    const u16* Arow = (m0 + sr < M) ? (gram + (long long)(m0 + sr)*512) : nullptr;
    const u16* Brow = wpt + (long long)(n0 + sr)*K;
    int lane = t & 63, wv = t >> 6;
    int fm = lane & 15, fq = lane >> 4;
    int arow = wv*16 + fm;
    f4 acc0 = {0,0,0,0}, acc1 = {0,0,0,0}, acc2 = {0,0,0,0}, acc3 = {0,0,0,0};
    for (int k0 = 0; k0 < K; k0 += 32){
        bf8 av = {};
        if (Arow) av = *(const bf8*)(Arow + k0 + sk);
        bf8 bv = *(const bf8*)(Brow + k0 + sk);
        *(bf8*)&As[sr][sk] = av;
        *(bf8*)&Bs[sr][sk] = bv;
        __syncthreads();
        bf8 af = *(const bf8*)&As[arow][fq*8];
        bf8 b0 = *(const bf8*)&Bs[ 0+fm][fq*8];
        bf8 b1 = *(const bf8*)&Bs[16+fm][fq*8];
        bf8 b2 = *(const bf8*)&Bs[32+fm][fq*8];
        bf8 b3 = *(const bf8*)&Bs[48+fm][fq*8];
        acc0 = __builtin_amdgcn_mfma_f32_16x16x32_bf16(af, b0, acc0, 0, 0, 0);
        acc1 = __builtin_amdgcn_mfma_f32_16x16x32_bf16(af, b1, acc1, 0, 0, 0);
        acc2 = __builtin_amdgcn_mfma_f32_16x16x32_bf16(af, b2, acc2, 0, 0, 0);
        acc3 = __builtin_amdgcn_mfma_f32_16x16x32_bf16(af, b3, acc3, 0, 0, 0);
        __syncthreads();
    }
    int col = n0 + fm;
    #pragma unroll
    for (int i = 0; i < 4; i++){
        int row = m0 + wv*16 + fq*4 + i;
        if (row >= M) continue;
        float* dp = dwe + (long long)row*512;
        dp[col]      = acc0[i];
        dp[col + 16] = acc1[i];
        dp[col + 32] = acc2[i];
        dp[col + 48] = acc3[i];
    }
}

// merged in-place expmap0: rows 0..4075 -> dwe, 4076..4163 -> emb_all
__global__ __launch_bounds__(128)
void k_expmap_all(float* __restrict__ dwe, float* __restrict__ dwe_ome,
                  float* __restrict__ emb_all, float* __restrict__ ome_all)
{
    __shared__ float red[128];
    int row = blockIdx.x, t = threadIdx.x;
    float* X; float* omeout;
    if (row < 4076){ X = dwe + (long long)row*512; omeout = dwe_ome + row; }
    else { int r = row - 4076; X = emb_all + (long long)r*512; omeout = ome_all + r; }
    float4 u = *(float4*)(X + t*4);
    red[t] = u.x*u.x + u.y*u.y + u.z*u.z + u.w*u.w; __syncthreads();
    for (int s = 64; s > 0; s >>= 1){ if (t < s) red[t] += red[t+s]; __syncthreads(); }
    float f, ome;
    expmap_scale_ome(red[0], &f, &ome);
    *(float4*)(X + t*4) = make_float4(u.x*f, u.y*f, u.z*f, u.w*f);
    if (t == 0) *omeout = ome;
}

// per doc-word row: 22 dots vs doc/sum/cand embeddings -> 1/pdist
__global__ __launch_bounds__(64)
void k_dots(const float* __restrict__ dwe, const float* __restrict__ dwe_ome,
            const float* __restrict__ doc_emb, const float* __restrict__ doc_ome,
            const float* __restrict__ sum_emb, const float* __restrict__ sum_ome,
            const float* __restrict__ cand_emb, const float* __restrict__ cand_ome,
            float* __restrict__ doc_inter, float* __restrict__ sum_inter,
            float* __restrict__ cand_inter)
{
    int row = blockIdx.x;            // b*1019 + l
    int b = row / 1019;
    int l = row - b*1019;
    int lane = threadIdx.x;
    const float* xr = dwe + (long long)row*512;
    float4 x0 = *(const float4*)(xr + lane*4);
    float4 x1 = *(const float4*)(xr + 256 + lane*4);
    float ox = dwe_ome[row];
    for (int c = 0; c < 22; c++){
        const float* y; float oy;
        if (c == 0){ y = doc_emb + b*512; oy = doc_ome[b]; }
        else if (c == 1){ y = sum_emb + b*512; oy = sum_ome[b]; }
        else { int cc = c - 2; y = cand_emb + (b*20 + cc)*512; oy = cand_ome[b*20 + cc]; }
        float4 y0 = *(const float4*)(y + lane*4);
        float4 y1v = *(const float4*)(y + 256 + lane*4);
        float s = x0.x*y0.x + x0.y*y0.y + x0.z*y0.z + x0.w*y0.w
                + x1.x*y1v.x + x1.y*y1v.y + x1.z*y1v.z + x1.w*y1v.w;
        for (int off = 32; off > 0; off >>= 1) s += __shfl_xor(s, off, 64);
        float dist = pdist_stable(ox, oy, s);
        if (lane == 0){
            float inv = 1.0f/fmaxf(dist, 1e-12f);
            if (c == 0) doc_inter[row] = inv;
            else if (c == 1) sum_inter[row] = inv;
            else cand_inter[((long long)(b*20 + (c-2)))*1019 + l] = inv;
        }
    }
}

// final: blocks 0..79 -> score[b,c]; 80..83 -> summary_score[b]; fp32 out
__global__ __launch_bounds__(256)
void k_final(const float* __restrict__ doc_inter, const float* __restrict__ sum_inter,
             const float* __restrict__ cand_inter,
             const float* __restrict__ doc_emb, const float* __restrict__ doc_ome,
             const float* __restrict__ sum_emb, const float* __restrict__ sum_ome,
             const float* __restrict__ cand_emb, const float* __restrict__ cand_ome,
             float* __restrict__ out)
{
    __shared__ float r0[256], r1[256], r2[256], r3[256];
    int j = blockIdx.x, t = threadIdx.x;
    int b; const float *a, *bb, *xe, *ye;
    float ox, oy; int outIdx;
    if (j < 80){
        b = j/20;
        a  = doc_inter + b*1019;
        bb = cand_inter + (long long)j*1019;
        xe = cand_emb + j*512; ox = cand_ome[j];
        ye = doc_emb + b*512;  oy = doc_ome[b];
        outIdx = j;
    } else {
        b = j - 80;
        a  = doc_inter + b*1019;
        bb = sum_inter + b*1019;
        xe = sum_emb + b*512;  ox = sum_ome[b];
        ye = doc_emb + b*512;  oy = doc_ome[b];
        outIdx = 80 + b;
    }
    float saa = 0.f, sbb = 0.f, sab = 0.f, st = 0.f;
    for (int l = t; l < 1019; l += 256){ float av = a[l], bv = bb[l]; saa += av*av; sbb += bv*bv; sab += av*bv; }
    for (int k = t; k < 512; k += 256) st += xe[k]*ye[k];
    r0[t] = saa; r1[t] = sbb; r2[t] = sab; r3[t] = st; __syncthreads();
    for (int s = 128; s > 0; s >>= 1){
        if (t < s){ r0[t] += r0[t+s]; r1[t] += r1[t+s]; r2[t] += r2[t+s]; r3[t] += r3[t+s]; }
        __syncthreads();
    }
    if (t == 0){
        float na = fmaxf(sqrtf(r0[0]), 1e-8f);
        float nb = fmaxf(sqrtf(r1[0]), 1e-8f);
        float cosv = r2[0] / (na*nb);
        float pd = pdist_stable(ox, oy, r3[0]);
        out[outIdx] = -pd*pd + cosv;
    }
}

extern "C" void kernel_launch(void* const* d_in, const int* in_sizes, int n_in,
                              void* d_out, int out_size, void* d_ws, size_t ws_size,
                              hipStream_t stream) {
    const float* text = (const float*)d_in[0];   // (4,512,768) fp32
    const float* summ = (const float*)d_in[1];   // (4,128,768)
    const float* cand = (const float*)d_in[2];   // (4,20,128,768)
    const float* W_d  = (const float*)d_in[3];   // (768,512)
    const float* W_s  = (const float*)d_in[4];
    const float* W_c  = (const float*)d_in[5];
    const float* W_p  = (const float*)d_in[6];   // (512,512)
    const float* cw1  = (const float*)d_in[7];   // (1,768,512)
    const float* cb1  = (const float*)d_in[8];   // (512,)
    const float* cw2  = (const float*)d_in[9];   // (2,768,512) = (1536,512)
    const float* cb2  = (const float*)d_in[10];  // (512,)
    float* out = (float*)d_out;                  // 84 fp32

    const int B = 4, C = 20, H = 768;

    char* base = (char*)d_ws;
    size_t off = 0;
    auto allocF = [&](size_t n)->float*{ float* p = (float*)(base + off); off += ((n*4) + 255) & ~(size_t)255; return p; };
    auto allocU = [&](size_t n)->u16*{ u16* p = (u16*)(base + off); off += ((n*2) + 255) & ~(size_t)255; return p; };

    float* smax = allocF(B*H);
    float* cmax = allocF(B*C*H);
    float* emb_all = allocF(88*512);   // raw -> scaled in place. 0..3 doc, 4..7 sum, 8..87 cand
    float* ome_all = allocF(88);
    float* doc_emb = emb_all;            float* doc_ome = ome_all;
    float* sum_emb = emb_all + 4*512;    float* sum_ome = ome_all + 4;
    float* cand_emb= emb_all + 8*512;    float* cand_ome= ome_all + 8;
    u16* textb = allocU(4*512*768);    // bf16 text
    u16* w1t   = allocU(512*768);      // w1^T  [n][k]
    u16* w2t   = allocU(512*1536);     // w2^T  [n][k]
    u16* wpt   = allocU(512*512);      // W_p^T [n][k]
    u16* gram  = allocU(4076*512);     // bf16 gram
    float* dwe = allocF(4076*512);     // fp32 doc_word emb
    float* dwe_ome   = allocF(4076);
    float* doc_inter = allocF(4076);
    float* sum_inter = allocF(4076);
    float* cand_inter= allocF(B*C*1019);

    // 1. max-reductions, 4-way l-split
    k_rowmax2<<<84*12, 256, 0, stream>>>(summ, cand, smax, cmax);

    // 2. pre-pass: bf16 convert text + transpose/convert weights
    k_prep<<<2176, 256, 0, stream>>>(text, cw1, cw2, W_p, textb, w1t, w2t, wpt);

    // 3. embedding GEMV (split 704 blocks) -> raw emb_all
    k_emb_gemv<<<704, 256, 0, stream>>>(text, smax, cmax, W_d, W_s, W_c, emb_all);

    // 4. MFMA conv GEMMs -> gram bf16
    dim3 gconv(64, 8);
    k_conv_mfma<<<gconv, 256, 0, stream>>>(textb, w1t, w2t, cb1, cb2, gram);

    // 5. MFMA W_p GEMM -> dwe fp32
    dim3 gwp(64, 8);
    k_wp_mfma<<<gwp, 256, 0, stream>>>(gram, wpt, dwe);

    // 6. merged expmap0 (dwe rows + emb rows)
    k_expmap_all<<<4076 + 88, 128, 0, stream>>>(dwe, dwe_ome, emb_all, ome_all);

    // 7. all pairwise dots -> 1/pdist
    k_dots<<<4076, 64, 0, stream>>>(dwe, dwe_ome, doc_emb, doc_ome, sum_emb, sum_ome,
                                    cand_emb, cand_ome, doc_inter, sum_inter, cand_inter);

    // 8. cos_sim reductions + pair pdist -> fp32 outputs
    k_final<<<84, 256, 0, stream>>>(doc_inter, sum_inter, cand_inter,
                                    doc_emb, doc_ome, sum_emb, sum_ome,
                                    cand_emb, cand_ome, out);
}

// Round 8
// 168.644 us; speedup vs baseline: 2.9457x; 1.0621x over previous
//
#include <hip/hip_runtime.h>
#include <math.h>

#define SQRTC  0.94868329805051381f       // sqrt(0.9)
#define MAXN   (0.996f/SQRTC)             // (1-PROJ_EPS)/sqrt(c)
#define OME_CLIP (1.0f - 0.996f*0.996f)   // 1 - c*maxnorm^2
#define TWO_OVER_SQRTC 2.1081851067789197f

typedef unsigned short u16;
typedef __attribute__((ext_vector_type(8))) short bf8;   // 8 bf16 (4 VGPRs)
typedef __attribute__((ext_vector_type(4))) float f4;    // MFMA C/D

__device__ __forceinline__ u16 f2bf(float f){
    union { float f; unsigned int i; } v; v.f = f;
    unsigned int x = v.i;
    unsigned int lsb = (x >> 16) & 1u;
    x += 0x7fffu + lsb;
    return (u16)(x >> 16);
}
__device__ __forceinline__ float bf2f(u16 u){
    union { unsigned int i; float f; } v; v.i = ((unsigned int)u) << 16; return v.f;
}

__device__ __forceinline__ float pdist_stable(float ome_x, float ome_y, float t){
    float u = 1.0f - ome_x, v = 1.0f - ome_y;   // c*x2, c*y2
    float den = fmaxf(1.0f - 1.8f*t + u*v, 1e-15f);
    float q = ome_x*ome_y/den;                   // = 1 - z^2
    q = fminf(fmaxf(q, 2.0e-7f), 1.0f);
    float z = sqrtf(fmaxf(1.0f - q, 0.0f));
    float at = 0.5f * logf((1.0f+z)*(1.0f+z)/q); // atanh(z)
    return TWO_OVER_SQRTC * at;
}

__device__ __forceinline__ void expmap_scale_ome(float sum, float* fout, float* omeout){
    float nraw = sqrtf(fmaxf(sum, 1e-30f));
    float n = fmaxf(nraw, 1e-15f);
    float sn = SQRTC*n;
    float th = tanhf(sn);
    float factor = th/sn;
    float gn = factor*nraw;
    if (gn > MAXN){ *fout = factor*(MAXN/gn); *omeout = OME_CLIP; }
    else { *fout = factor; *omeout = fmaxf((1.0f-th)*(1.0f+th), 1e-12f); }
}

// D1: blocks 0..1007 rowmax; 1008..3183 prep (text cvt + weight transposes).
// rowmax and prep are mutually independent (G16-safe).
__global__ __launch_bounds__(256)
void k_stage1(const float* __restrict__ summ, const float* __restrict__ cand,
              const float* __restrict__ text,
              const float* __restrict__ w1, const float* __restrict__ w2,
              const float* __restrict__ wp,
              float* __restrict__ smax, float* __restrict__ cmax,
              u16* __restrict__ textb, u16* __restrict__ w1t,
              u16* __restrict__ w2t, u16* __restrict__ wpt)
{
    __shared__ float shm[1056];
    int bx = blockIdx.x;
    int t = threadIdx.x;
    if (bx < 1008){
        // rowmax: 84 rows x 12 h-tiles, 4 l-groups of 32
        int row = bx / 12, ht = bx - row*12;
        int lane = t & 63, lg = t >> 6;
        int h = ht*64 + lane;
        const float* in = (row < 4) ? (summ + (long long)row*128*768)
                                    : (cand + (long long)(row-4)*128*768);
        const float* p = in + (long long)(lg*32)*768 + h;
        float m = -INFINITY;
        #pragma unroll 8
        for (int l = 0; l < 32; l++) m = fmaxf(m, p[l*768]);
        shm[t] = m; __syncthreads();
        if (t < 64){
            float mm = fmaxf(fmaxf(shm[t], shm[t+64]), fmaxf(shm[t+128], shm[t+192]));
            if (row < 4) smax[row*768 + h] = mm;
            else cmax[(row-4)*768 + h] = mm;
        }
        return;
    }
    int pb = bx - 1008;
    if (pb < 768){
        int base = pb*2048 + t*8;
        float4 a = *(const float4*)(text + base);
        float4 b = *(const float4*)(text + base + 4);
        *(ushort4*)(textb + base)     = make_ushort4(f2bf(a.x), f2bf(a.y), f2bf(a.z), f2bf(a.w));
        *(ushort4*)(textb + base + 4) = make_ushort4(f2bf(b.x), f2bf(b.y), f2bf(b.z), f2bf(b.w));
        return;
    }
    int j = pb - 768;
    const float* in; u16* outp; int K;
    if (j < 384){ in = w1; outp = w1t; K = 768; }
    else if (j < 1152){ j -= 384; in = w2; outp = w2t; K = 1536; }
    else { j -= 1152; in = wp; outp = wpt; K = 512; }
    const int N = 512, ntile = N/32;
    int k0 = (j/ntile)*32, n0 = (j - (j/ntile)*ntile)*32;
    int tx = t & 31, ty = t >> 5;   // ty 0..7
    #pragma unroll
    for (int i = 0; i < 4; i++)
        shm[(ty*4+i)*33 + tx] = in[(long long)(k0 + ty*4 + i)*N + n0 + tx];
    __syncthreads();
    #pragma unroll
    for (int i = 0; i < 4; i++)
        outp[(long long)(n0 + ty*4 + i)*K + k0 + tx] = f2bf(shm[tx*33 + ty*4+i]);
}

// D2: blocks 0..511 conv MFMA (reads D1 textb/w1t/w2t); 512..1215 emb_gemv
// (reads D1 smax/cmax). The two jobs are mutually independent.
__global__ __launch_bounds__(256)
void k_stage2(const u16* __restrict__ textb,
              const u16* __restrict__ w1t, const u16* __restrict__ w2t,
              const float* __restrict__ cb1, const float* __restrict__ cb2,
              const float* __restrict__ text,
              const float* __restrict__ smax, const float* __restrict__ cmax,
              const float* __restrict__ W_d, const float* __restrict__ W_s,
              const float* __restrict__ W_c,
              u16* __restrict__ gram, float* __restrict__ emb_all)
{
    __shared__ char smem[8192];
    int bx = blockIdx.x;
    int t = threadIdx.x;
    if (bx < 512){
        // ---- conv MFMA ----
        u16 (*As)[32] = (u16(*)[32])smem;          // [64][32]
        u16 (*Bs)[32] = (u16(*)[32])(smem + 4096); // [64][32]
        int xx = bx & 63, yy = bx >> 6;
        int job = xx & 1;
        int m0 = (xx >> 1) * 64;
        int n0 = yy * 64;
        int K   = job ? 1536 : 768;
        int M   = job ? 2036 : 2040;
        int rpb = job ? 509 : 510;
        int ob  = job ? 510 : 0;
        const u16* Bt = job ? w2t : w1t;
        const float* bias = job ? cb2 : cb1;
        int sr = t >> 2, sk = (t & 3) << 3;
        const u16* Arow = nullptr;
        { int gm = m0 + sr; if (gm < M){ int b = gm/rpb, l = gm - b*rpb;
            Arow = textb + (long long)b*393216 + (long long)(l+1)*768; } }
        const u16* Brow = Bt + (long long)(n0 + sr)*K;
        int lane = t & 63, wv = t >> 6;
        int fm = lane & 15, fq = lane >> 4;
        int arow = wv*16 + fm;
        f4 acc0 = {0,0,0,0}, acc1 = {0,0,0,0}, acc2 = {0,0,0,0}, acc3 = {0,0,0,0};
        for (int k0 = 0; k0 < K; k0 += 32){
            bf8 av = {};
            if (Arow) av = *(const bf8*)(Arow + k0 + sk);
            bf8 bv = *(const bf8*)(Brow + k0 + sk);
            *(bf8*)&As[sr][sk] = av;
            *(bf8*)&Bs[sr][sk] = bv;
            __syncthreads();
            bf8 af = *(const bf8*)&As[arow][fq*8];
            bf8 b0 = *(const bf8*)&Bs[ 0+fm][fq*8];
            bf8 b1 = *(const bf8*)&Bs[16+fm][fq*8];
            bf8 b2 = *(const bf8*)&Bs[32+fm][fq*8];
            bf8 b3 = *(const bf8*)&Bs[48+fm][fq*8];
            acc0 = __builtin_amdgcn_mfma_f32_16x16x32_bf16(af, b0, acc0, 0, 0, 0);
            acc1 = __builtin_amdgcn_mfma_f32_16x16x32_bf16(af, b1, acc1, 0, 0, 0);
            acc2 = __builtin_amdgcn_mfma_f32_16x16x32_bf16(af, b2, acc2, 0, 0, 0);
            acc3 = __builtin_amdgcn_mfma_f32_16x16x32_bf16(af, b3, acc3, 0, 0, 0);
            __syncthreads();
        }
        int col = n0 + fm;
        float bv0 = bias[col], bv1 = bias[col+16], bv2 = bias[col+32], bv3 = bias[col+48];
        #pragma unroll
        for (int i = 0; i < 4; i++){
            int row = m0 + wv*16 + fq*4 + i;
            if (row >= M) continue;
            int b = row/rpb, l = row - b*rpb;
            long long orow = (long long)b*1019 + ob + l;
            u16* gp = gram + orow*512;
            gp[col]      = f2bf(fmaxf(acc0[i] + bv0, 0.f));
            gp[col + 16] = f2bf(fmaxf(acc1[i] + bv1, 0.f));
            gp[col + 32] = f2bf(fmaxf(acc2[i] + bv2, 0.f));
            gp[col + 48] = f2bf(fmaxf(acc3[i] + bv3, 0.f));
        }
        return;
    }
    // ---- emb_gemv: 88 rows x 8 col-tiles ----
    {
        int eb = bx - 512;
        int row = eb >> 3, nt = eb & 7;
        float* a   = (float*)smem;          // 768 floats
        float* red = (float*)smem + 768;    // 256 floats
        const float* A; const float* W;
        if (row < 4){ A = text + (long long)row*512*768; W = W_d; }
        else if (row < 8){ A = smax + (long long)(row-4)*768; W = W_s; }
        else { A = cmax + (long long)(row-8)*768; W = W_c; }
        for (int k = t; k < 768; k += 256) a[k] = A[k];
        __syncthreads();
        int lane = t & 63, kg = t >> 6;
        int col = nt*64 + lane;
        const float* Wp = W + (long long)(kg*192)*512 + col;
        float acc = 0.f;
        #pragma unroll 8
        for (int k = 0; k < 192; k++) acc += a[kg*192 + k] * Wp[k*512];
        red[t] = acc; __syncthreads();
        if (t < 64) emb_all[(long long)row*512 + col] = red[t] + red[t+64] + red[t+128] + red[t+192];
    }
}

// D3: blocks 0..511 W_p MFMA (reads D2 gram); 512..599 expmap88 (reads D2 emb_all).
__global__ __launch_bounds__(256)
void k_stage3(const u16* __restrict__ gram, const u16* __restrict__ wpt,
              u16* __restrict__ dwe_b,
              float* __restrict__ emb_all, float* __restrict__ ome_all)
{
    __shared__ char smem[8192];
    int bx = blockIdx.x;
    int t = threadIdx.x;
    if (bx < 512){
        u16 (*As)[32] = (u16(*)[32])smem;
        u16 (*Bs)[32] = (u16(*)[32])(smem + 4096);
        const int K = 512, M = 4076;
        int m0 = (bx >> 3) * 64;
        int n0 = (bx & 7) * 64;
        int sr = t >> 2, sk = (t & 3) << 3;
        const u16* Arow = (m0 + sr < M) ? (gram + (long long)(m0 + sr)*512) : nullptr;
        const u16* Brow = wpt + (long long)(n0 + sr)*K;
        int lane = t & 63, wv = t >> 6;
        int fm = lane & 15, fq = lane >> 4;
        int arow = wv*16 + fm;
        f4 acc0 = {0,0,0,0}, acc1 = {0,0,0,0}, acc2 = {0,0,0,0}, acc3 = {0,0,0,0};
        for (int k0 = 0; k0 < K; k0 += 32){
            bf8 av = {};
            if (Arow) av = *(const bf8*)(Arow + k0 + sk);
            bf8 bv = *(const bf8*)(Brow + k0 + sk);
            *(bf8*)&As[sr][sk] = av;
            *(bf8*)&Bs[sr][sk] = bv;
            __syncthreads();
            bf8 af = *(const bf8*)&As[arow][fq*8];
            bf8 b0 = *(const bf8*)&Bs[ 0+fm][fq*8];
            bf8 b1 = *(const bf8*)&Bs[16+fm][fq*8];
            bf8 b2 = *(const bf8*)&Bs[32+fm][fq*8];
            bf8 b3 = *(const bf8*)&Bs[48+fm][fq*8];
            acc0 = __builtin_amdgcn_mfma_f32_16x16x32_bf16(af, b0, acc0, 0, 0, 0);
            acc1 = __builtin_amdgcn_mfma_f32_16x16x32_bf16(af, b1, acc1, 0, 0, 0);
            acc2 = __builtin_amdgcn_mfma_f32_16x16x32_bf16(af, b2, acc2, 0, 0, 0);
            acc3 = __builtin_amdgcn_mfma_f32_16x16x32_bf16(af, b3, acc3, 0, 0, 0);
            __syncthreads();
        }
        int col = n0 + fm;
        #pragma unroll
        for (int i = 0; i < 4; i++){
            int row = m0 + wv*16 + fq*4 + i;
            if (row >= M) continue;
            u16* dp = dwe_b + (long long)row*512;
            dp[col]      = f2bf(acc0[i]);
            dp[col + 16] = f2bf(acc1[i]);
            dp[col + 32] = f2bf(acc2[i]);
            dp[col + 48] = f2bf(acc3[i]);
        }
        return;
    }
    // ---- expmap0 in-place on the 88 emb rows (256 threads, 2 elems each) ----
    {
        float* red = (float*)smem;   // 256 floats
        int row = bx - 512;
        float* X = emb_all + (long long)row*512;
        float2 u = *(float2*)(X + t*2);
        red[t] = u.x*u.x + u.y*u.y; __syncthreads();
        for (int s = 128; s > 0; s >>= 1){ if (t < s) red[t] += red[t+s]; __syncthreads(); }
        float f, ome;
        expmap_scale_ome(red[0], &f, &ome);
        *(float2*)(X + t*2) = make_float2(u.x*f, u.y*f);
        if (t == 0) ome_all[row] = ome;
    }
}

// D4: per doc-word row, fused expmap0 + 22 dots -> 1/pdist. One wave per row.
__global__ __launch_bounds__(64)
void k_dots(const u16* __restrict__ dwe_b,
            const float* __restrict__ emb_all, const float* __restrict__ ome_all,
            float* __restrict__ doc_inter, float* __restrict__ sum_inter,
            float* __restrict__ cand_inter)
{
    int row = blockIdx.x;            // b*1019 + l
    int b = row / 1019;
    int l = row - b*1019;
    int lane = threadIdx.x;
    bf8 xr = *(const bf8*)(dwe_b + (long long)row*512 + lane*8);
    float x[8];
    #pragma unroll
    for (int j = 0; j < 8; j++) x[j] = bf2f(((u16*)&xr)[j]);
    float ss = 0.f;
    #pragma unroll
    for (int j = 0; j < 8; j++) ss += x[j]*x[j];
    #pragma unroll
    for (int off = 32; off > 0; off >>= 1) ss += __shfl_xor(ss, off, 64);
    float f, ox;
    expmap_scale_ome(ss, &f, &ox);
    #pragma unroll
    for (int j = 0; j < 8; j++) x[j] *= f;

    for (int c = 0; c < 22; c++){
        int ei = (c == 0) ? b : (c == 1) ? (4 + b) : (8 + b*20 + (c-2));
        const float* y = emb_all + (long long)ei*512 + lane*8;
        float oy = ome_all[ei];
        float4 y0 = *(const float4*)(y);
        float4 y1 = *(const float4*)(y + 4);
        float s = x[0]*y0.x + x[1]*y0.y + x[2]*y0.z + x[3]*y0.w
                + x[4]*y1.x + x[5]*y1.y + x[6]*y1.z + x[7]*y1.w;
        #pragma unroll
        for (int off = 32; off > 0; off >>= 1) s += __shfl_xor(s, off, 64);
        float dist = pdist_stable(ox, oy, s);
        if (lane == 0){
            float inv = 1.0f/fmaxf(dist, 1e-12f);
            if (c == 0) doc_inter[row] = inv;
            else if (c == 1) sum_inter[row] = inv;
            else cand_inter[((long long)(b*20 + (c-2)))*1019 + l] = inv;
        }
    }
}

// D5: blocks 0..79 -> score[b,c]; 80..83 -> summary_score[b]; fp32 out
__global__ __launch_bounds__(256)
void k_final(const float* __restrict__ doc_inter, const float* __restrict__ sum_inter,
             const float* __restrict__ cand_inter,
             const float* __restrict__ emb_all, const float* __restrict__ ome_all,
             float* __restrict__ out)
{
    __shared__ float r0[256], r1[256], r2[256], r3[256];
    int j = blockIdx.x, t = threadIdx.x;
    int b; const float *a, *bb; int xi, yi; int outIdx;
    if (j < 80){
        b = j/20;
        a  = doc_inter + b*1019;
        bb = cand_inter + (long long)j*1019;
        xi = 8 + j; yi = b;
        outIdx = j;
    } else {
        b = j - 80;
        a  = doc_inter + b*1019;
        bb = sum_inter + b*1019;
        xi = 4 + b; yi = b;
        outIdx = 80 + b;
    }
    const float* xe = emb_all + (long long)xi*512;
    const float* ye = emb_all + (long long)yi*512;
    float ox = ome_all[xi], oy = ome_all[yi];
    float saa = 0.f, sbb = 0.f, sab = 0.f, st = 0.f;
    for (int l = t; l < 1019; l += 256){ float av = a[l], bv = bb[l]; saa += av*av; sbb += bv*bv; sab += av*bv; }
    for (int k = t; k < 512; k += 256) st += xe[k]*ye[k];
    r0[t] = saa; r1[t] = sbb; r2[t] = sab; r3[t] = st; __syncthreads();
    for (int s = 128; s > 0; s >>= 1){
        if (t < s){ r0[t] += r0[t+s]; r1[t] += r1[t+s]; r2[t] += r2[t+s]; r3[t] += r3[t+s]; }
        __syncthreads();
    }
    if (t == 0){
        float na = fmaxf(sqrtf(r0[0]), 1e-8f);
        float nb = fmaxf(sqrtf(r1[0]), 1e-8f);
        float cosv = r2[0] / (na*nb);
        float pd = pdist_stable(ox, oy, r3[0]);
        out[outIdx] = -pd*pd + cosv;
    }
}

extern "C" void kernel_launch(void* const* d_in, const int* in_sizes, int n_in,
                              void* d_out, int out_size, void* d_ws, size_t ws_size,
                              hipStream_t stream) {
    const float* text = (const float*)d_in[0];   // (4,512,768) fp32
    const float* summ = (const float*)d_in[1];   // (4,128,768)
    const float* cand = (const float*)d_in[2];   // (4,20,128,768)
    const float* W_d  = (const float*)d_in[3];   // (768,512)
    const float* W_s  = (const float*)d_in[4];
    const float* W_c  = (const float*)d_in[5];
    const float* W_p  = (const float*)d_in[6];   // (512,512)
    const float* cw1  = (const float*)d_in[7];   // (1,768,512)
    const float* cb1  = (const float*)d_in[8];   // (512,)
    const float* cw2  = (const float*)d_in[9];   // (2,768,512) = (1536,512)
    const float* cb2  = (const float*)d_in[10];  // (512,)
    float* out = (float*)d_out;                  // 84 fp32

    const int B = 4, C = 20, H = 768;

    char* base = (char*)d_ws;
    size_t off = 0;
    auto allocF = [&](size_t n)->float*{ float* p = (float*)(base + off); off += ((n*4) + 255) & ~(size_t)255; return p; };
    auto allocU = [&](size_t n)->u16*{ u16* p = (u16*)(base + off); off += ((n*2) + 255) & ~(size_t)255; return p; };

    float* smax = allocF(B*H);
    float* cmax = allocF(B*C*H);
    float* emb_all = allocF(88*512);   // 0..3 doc, 4..7 sum, 8..87 cand
    float* ome_all = allocF(88);
    u16* textb = allocU(4*512*768);
    u16* w1t   = allocU(512*768);
    u16* w2t   = allocU(512*1536);
    u16* wpt   = allocU(512*512);
    u16* gram  = allocU(4076*512);
    u16* dwe_b = allocU(4076*512);     // bf16 raw doc_word pre-emb
    float* doc_inter = allocF(4076);
    float* sum_inter = allocF(4076);
    float* cand_inter= allocF(B*C*1019);

    // D1: rowmax + prep (independent jobs)
    k_stage1<<<3184, 256, 0, stream>>>(summ, cand, text, cw1, cw2, W_p,
                                       smax, cmax, textb, w1t, w2t, wpt);

    // D2: conv MFMA + emb_gemv (independent jobs; both depend only on D1/inputs)
    k_stage2<<<1216, 256, 0, stream>>>(textb, w1t, w2t, cb1, cb2,
                                       text, smax, cmax, W_d, W_s, W_c,
                                       gram, emb_all);

    // D3: W_p MFMA + expmap88 (independent jobs; depend only on D2)
    k_stage3<<<600, 256, 0, stream>>>(gram, wpt, dwe_b, emb_all, ome_all);

    // D4: fused expmap + pairwise dots -> 1/pdist
    k_dots<<<4076, 64, 0, stream>>>(dwe_b, emb_all, ome_all,
                                    doc_inter, sum_inter, cand_inter);

    // D5: cos_sim reductions + pair pdist -> fp32 outputs
    k_final<<<84, 256, 0, stream>>>(doc_inter, sum_inter, cand_inter,
                                    emb_all, ome_all, out);
}